// Round 9
// baseline (394.843 us; speedup 1.0000x reference)
//
#include <hip/hip_runtime.h>
#include <hip/hip_bf16.h>

// DecoderLayer: B=8, T=S=1024, D=512, H=8, depth=64, F=2048. fp32 in/out.
// Outputs (concat in d_out): out3 [8,1024,512], sa_w [64,1024,1024], ca_w [64,1024,1024].
// Round 9: attention KVBLK 32->64 (half the barriers, 2x MFMA per phase,
// dbuf K/V with counted vmcnt, 50KB LDS, 3 blocks/CU) + s_setprio around the
// MFMA/exp cluster. Rest unchanged from round 8. 10 nodes.

using bf16 = __hip_bfloat16;
typedef __attribute__((ext_vector_type(8))) short bf16x8v;
typedef __attribute__((ext_vector_type(4))) float f32x4;
typedef __attribute__((ext_vector_type(2))) float f32x2;
typedef __attribute__((ext_vector_type(2))) unsigned int u32x2;

#define DEVI __device__ __forceinline__

// 0.125 (1/sqrt(depth)) * log2(e): logits computed directly in exp2 units.
#define QSCL 0.18033688011112042f

DEVI short f2bs(float f) {
  bf16 h = __float2bfloat16(f);
  return *reinterpret_cast<short*>(&h);
}
DEVI bf16 f2b(float f) { return __float2bfloat16(f); }
DEVI float ex2(float x) { return __builtin_amdgcn_exp2f(x); }

DEVI void gload16(const bf16* g, bf16* l) {
  __builtin_amdgcn_global_load_lds(
      (const __attribute__((address_space(1))) void*)g,
      (__attribute__((address_space(3))) void*)l, 16, 0, 0);
}

// wave-uniform counted vmcnt wait (immediates only)
DEVI void vmwait(int n) {
  if (n == 0)       asm volatile("s_waitcnt vmcnt(0)" ::: "memory");
  else if (n == 8)  asm volatile("s_waitcnt vmcnt(8)" ::: "memory");
  else              asm volatile("s_waitcnt vmcnt(4)" ::: "memory");
}
#define SBAR() __builtin_amdgcn_sched_barrier(0)

// ---------------- fused prep: casts + weight transposes + bias concat ----------
struct WDesc { const float* src; bf16* dst; int K; int N; int toff; float scl; };
struct PrepPack {
  const float* x; const float* enc; bf16* xb; bf16* encb;
  WDesc d[10];
  const float* bsrc[6]; float bscl[6]; float* bdst;
};

__global__ __launch_bounds__(256) void prep_k(PrepPack p) {
  const int bid = blockIdx.x;
  if (bid < 8192) {
    const float* s = (bid < 4096) ? p.x : p.enc;
    bf16* d = (bid < 4096) ? p.xb : p.encb;
    long i = ((long)(bid & 4095) * 256 + threadIdx.x) * 4;
    f32x4 v = *reinterpret_cast<const f32x4*>(s + i);
    union { short sh[4]; long l; } u;
    u.sh[0] = f2bs(v[0]); u.sh[1] = f2bs(v[1]); u.sh[2] = f2bs(v[2]); u.sh[3] = f2bs(v[3]);
    *reinterpret_cast<long*>(d + i) = u.l;
    return;
  }
  if (bid < 12288) {
    const int t = bid - 8192;
    int wi = 0;
#pragma unroll
    for (int i = 1; i < 10; i++)
      if (t >= p.d[i].toff) wi = i;
    const WDesc d = p.d[wi];
    const int lt = t - d.toff;
    const int nx = d.N >> 5;
    const int n0 = (lt % nx) * 32, k0 = (lt / nx) * 32;
    __shared__ float tile[32][33];
    const int tx = threadIdx.x & 31, ty = threadIdx.x >> 5;
#pragma unroll
    for (int i = 0; i < 32; i += 8)
      tile[ty + i][tx] = d.src[(long)(k0 + ty + i) * d.N + n0 + tx] * d.scl;
    __syncthreads();
#pragma unroll
    for (int i = 0; i < 32; i += 8)
      d.dst[(long)(n0 + ty + i) * d.K + k0 + tx] = f2b(tile[tx][ty + i]);
    return;
  }
  const int i = bid - 12288;
  const int e = threadIdx.x * 2;
  f32x2 v = *reinterpret_cast<const f32x2*>(p.bsrc[i] + e);
  v[0] *= p.bscl[i]; v[1] *= p.bscl[i];
  *reinterpret_cast<f32x2*>(p.bdst + i * 512 + e) = v;
}

// ---------------- V transpose body: v[b*1024+s][h*64+d] -> vt[bh][d][s] ----
DEVI void vtrans_body(int bx, int by, int bz, const bf16* __restrict__ v, int ldv,
                      bf16* __restrict__ vt, bf16* tile /* [32*33] */) {
  int b = bz >> 3, h = bz & 7;
  const bf16* src = v + (long)b * 1024 * ldv + h * 64;
  bf16* dst = vt + (long)bz * 64 * 1024;
  int tx = threadIdx.x & 31, ty = threadIdx.x >> 5;
  int d0 = bx * 32, s0 = by * 32;
#pragma unroll
  for (int i = 0; i < 32; i += 8)
    tile[(ty + i) * 33 + tx] = src[(long)(s0 + ty + i) * ldv + d0 + tx];
  __syncthreads();
#pragma unroll
  for (int i = 0; i < 32; i += 8)
    dst[(long)(d0 + ty + i) * 1024 + s0 + tx] = tile[tx * 33 + ty + i];
}

__global__ __launch_bounds__(256) void transpose_v_bh_k(const bf16* __restrict__ v, int ldv,
                                                        bf16* __restrict__ vt) {
  __shared__ bf16 tile[32 * 33];
  vtrans_body(blockIdx.x, blockIdx.y, blockIdx.z, v, ldv, vt, tile);
}

// ---------------- GEMM body (shared) ------------
template <int FM, int FN, typename TC, bool RELU>
DEVI void gemm_body(int bid, int nblocks,
                    const bf16* __restrict__ A, int lda,
                    const bf16* __restrict__ Bt, int ldb,
                    TC* __restrict__ C, int ldc,
                    const float* __restrict__ bias, int K, int tiles_n,
                    bf16* sA, bf16* sB) {
  constexpr int BM = 32 * FM, BN = 32 * FN;
  const int tm8 = (nblocks / tiles_n) >> 3;
  const int r8 = bid >> 3;
  const int tm = (bid & 7) + ((r8 % tm8) << 3);
  const int tn = r8 / tm8;
  const int tid = threadIdx.x, wave = tid >> 6, lane = tid & 63;
  const int wr = wave >> 1, wc = wave & 1;
  const int l16 = lane & 15, lhi = lane >> 4;
  const int srow = lane >> 2, scol = (lane & 3) * 8;

  const bf16* Ab = A + (long)(tm * BM + wave * (BM / 4) + srow) * lda + scol;
  const bf16* Bb = Bt + (long)(tn * BN + wave * (BN / 4) + srow) * ldb + scol;

  auto stage = [&](int buf, int k0) {
#pragma unroll
    for (int i = 0; i < BM / 64; i++)
      gload16(Ab + (long)(i * 16) * lda + k0, sA + buf * BM * 32 + (wave * (BM / 4) + i * 16) * 32);
#pragma unroll
    for (int i = 0; i < BN / 64; i++)
      gload16(Bb + (long)(i * 16) * ldb + k0, sB + buf * BN * 32 + (wave * (BN / 4) + i * 16) * 32);
  };

  stage(0, 0);
  __syncthreads();

  f32x4 acc[FM][FN] = {};
  int cur = 0;
  for (int k0 = 0; k0 < K; k0 += 32) {
    if (k0 + 32 < K) stage(cur ^ 1, k0 + 32);
    bf16x8v af[FM], bfr[FN];
#pragma unroll
    for (int m = 0; m < FM; m++)
      af[m] = *reinterpret_cast<const bf16x8v*>(
          sA + cur * BM * 32 + (wr * 16 * FM + m * 16 + l16) * 32 + lhi * 8);
#pragma unroll
    for (int n = 0; n < FN; n++)
      bfr[n] = *reinterpret_cast<const bf16x8v*>(
          sB + cur * BN * 32 + (wc * 16 * FN + n * 16 + l16) * 32 + lhi * 8);
#pragma unroll
    for (int m = 0; m < FM; m++)
#pragma unroll
      for (int n = 0; n < FN; n++)
        acc[m][n] = __builtin_amdgcn_mfma_f32_16x16x32_bf16(af[m], bfr[n], acc[m][n], 0, 0, 0);
    if (k0 + 32 < K) {
      __syncthreads();
      cur ^= 1;
    }
  }

#pragma unroll
  for (int m = 0; m < FM; m++) {
    const int gr0 = tm * BM + wr * 16 * FM + m * 16 + lhi * 4;
#pragma unroll
    for (int n = 0; n < FN; n++) {
      const int gc = tn * BN + wc * 16 * FN + n * 16 + l16;
      const float bv = bias ? bias[gc] : 0.f;
#pragma unroll
      for (int j = 0; j < 4; j++) {
        float v = acc[m][n][j] + bv;
        if (RELU) v = fmaxf(v, 0.f);
        if constexpr (sizeof(TC) == 4)
          C[(long)(gr0 + j) * ldc + gc] = v;
        else
          C[(long)(gr0 + j) * ldc + gc] = f2b(v);
      }
    }
  }
}

template <int FM, int FN, typename TC, bool RELU>
__global__ __launch_bounds__(256) void gemm_gl_k(
    const bf16* __restrict__ A, int lda, const bf16* __restrict__ Bt, int ldb,
    TC* __restrict__ C, int ldc, const float* __restrict__ bias, int K, int tiles_n) {
  __shared__ bf16 sA[2 * 32 * FM * 32];
  __shared__ bf16 sB[2 * 32 * FN * 32];
  gemm_body<FM, FN, TC, RELU>(blockIdx.x, gridDim.x, A, lda, Bt, ldb, C, ldc,
                              bias, K, tiles_n, sA, sB);
}

// merged q2 GEMM + vt2 transpose
__global__ __launch_bounds__(256) void q2vt_k(
    const bf16* __restrict__ A, const bf16* __restrict__ Bt, bf16* __restrict__ C,
    const float* __restrict__ bias, const bf16* __restrict__ v2, bf16* __restrict__ vt2) {
  __shared__ __align__(16) char smem[24576];
  if (blockIdx.x < 512) {
    gemm_body<2, 4, bf16, false>(blockIdx.x, 512, A, 512, Bt, 512, C, 512, bias, 512, 4,
                                 (bf16*)smem, (bf16*)smem + 2 * 64 * 32);
  } else {
    const int t = blockIdx.x - 512;
    vtrans_body(t & 1, (t >> 1) & 31, t >> 6, v2, 1024, vt2, (bf16*)smem);
  }
}

// ---------------- attention body: KVBLK=64 counted-vmcnt 2-pass flash ----------
// LDS 51200 B: Kst[2][4096] | Vst[2][4096] | pst[4][32*72] (bf16)
// K chunk [64 keys][64 d]; V chunk [64 d][64 keys]. Per chunk: vmwait(own) ->
// s_barrier -> prefetch t(ch+1) -> setprio(1) QK/exp/PV setprio(0) -> P flush.
template <bool CAUSAL>
DEVI void attn_body(int bid, char* smem,
                    const bf16* __restrict__ Qm, int ldq,
                    const bf16* __restrict__ Km, int ldk,
                    const bf16* __restrict__ vt,
                    float* __restrict__ P, bf16* __restrict__ ctx) {
  bf16* Kst = (bf16*)smem;      // 2 x 4096 elems
  bf16* Vst = Kst + 8192;       // 2 x 4096
  bf16* pst = Vst + 8192;       // 4 x 2304 (32 rows x 72)
  const int bh = bid & 63;
  const int g = bid >> 6;
  const int qx = CAUSAL ? ((g < 4) ? g : 11 - g) : g;  // anti-correlated pairs
  const int b = bh >> 3, h = bh & 7;
  const int tid = threadIdx.x, wave = tid >> 6, lane = tid & 63;
  const int l16 = lane & 15, lhi = lane >> 4;
  const int q0 = qx * 128 + wave * 32;
  const bf16* Qb = Qm + (long)(b * 1024 + q0) * ldq + h * 64;
  const bf16* Kb = Km + (long)b * 1024 * ldk + h * 64;
  const bf16* Vb = vt + (long)bh * 64 * 1024;

  // chunks of 64 keys
  const int nchw = CAUSAL ? (2 * qx + (wave >> 1) + 1) : 16;  // wave compute chunks
  const int nchb = CAUSAL ? (2 * qx + 2) : 16;                // block staging chunks
  const int qrel = (wave & 1) * 32;                           // diag row offset

  // staging sources: row = tid>>3 (and +32 second round), granule swizzled
  const bf16* ksrc = Kb + (long)(tid >> 3) * ldk + ((tid & 7) ^ ((tid >> 3) & 7)) * 8;
  const bf16* vsrc = Vb + (long)(tid >> 3) * 1024 + ((tid & 7) ^ ((tid >> 3) & 7)) * 8;

  // swizzled read granule offsets (elems): row&7 == l16&7 for all frag rows
  int sw[2];
#pragma unroll
  for (int ks = 0; ks < 2; ks++)
    sw[ks] = (((ks * 4 + lhi) ^ (l16 & 7)) << 3);

  bf16x8v qB[2][2];
#pragma unroll
  for (int m = 0; m < 2; m++)
#pragma unroll
    for (int ks = 0; ks < 2; ks++)
      qB[m][ks] = *reinterpret_cast<const bf16x8v*>(
          Qb + (long)(m * 16 + l16) * ldq + ks * 32 + lhi * 8);

  float ll[2] = {0.f, 0.f};

  // ================ pass 1: l-sum, K double-buffered ================
  gload16(ksrc, Kst + wave * 512);
  gload16(ksrc + (long)32 * ldk, Kst + 2048 + wave * 512);
#pragma unroll 1
  for (int ch = 0; ch < nchb; ch++) {
    vmwait(0);
    SBAR();
    __builtin_amdgcn_s_barrier();
    SBAR();
    if (ch + 1 < nchb) {
      const bf16* kp = ksrc + (long)(ch + 1) * 64 * ldk;
      bf16* kd = Kst + ((ch + 1) & 1) * 4096 + wave * 512;
      gload16(kp, kd);
      gload16(kp + (long)32 * ldk, kd + 2048);
    }
    if (ch < nchw) {
      const int bo = (ch & 1) * 4096;
      bf16x8v kf[4][2];
#pragma unroll
      for (int cc = 0; cc < 4; cc++) {
        const int row = cc * 16 + l16;
#pragma unroll
        for (int ks = 0; ks < 2; ks++)
          kf[cc][ks] = *reinterpret_cast<const bf16x8v*>(&Kst[bo + row * 64 + sw[ks]]);
      }
      const bool diag = CAUSAL && (ch == nchw - 1);
      __builtin_amdgcn_s_setprio(1);
#pragma unroll
      for (int m = 0; m < 2; m++) {
        f32x4 s[4] = {};
#pragma unroll
        for (int cc = 0; cc < 4; cc++) {
          s[cc] = __builtin_amdgcn_mfma_f32_16x16x32_bf16(kf[cc][0], qB[m][0], s[cc], 0, 0, 0);
          s[cc] = __builtin_amdgcn_mfma_f32_16x16x32_bf16(kf[cc][1], qB[m][1], s[cc], 0, 0, 0);
        }
        if (diag) {
          const int rq = qrel + m * 16 + l16;
#pragma unroll
          for (int cc = 0; cc < 4; cc++)
#pragma unroll
            for (int j = 0; j < 4; j++)
              s[cc][j] = (cc * 16 + lhi * 4 + j <= rq) ? s[cc][j] : -1e30f;  // exp2->0
        }
        float sum = 0.f;
#pragma unroll
        for (int cc = 0; cc < 4; cc++)
#pragma unroll
          for (int j = 0; j < 4; j++) sum += ex2(s[cc][j]);
        ll[m] += sum;
      }
      __builtin_amdgcn_s_setprio(0);
    }
  }
  __syncthreads();  // pass boundary

  float il[2];
#pragma unroll
  for (int m = 0; m < 2; m++) {
    float lo = ll[m];
    lo += __shfl_xor(lo, 16);
    lo += __shfl_xor(lo, 32);
    il[m] = 1.f / lo;
  }

  // ================ pass 2: P write + PV, K+V double-buffered ================
  f32x4 pv[2][4] = {};
  float* Pg = P + (long)bh * 1024 * 1024 + (long)q0 * 1024;
  gload16(ksrc, Kst + wave * 512);
  gload16(ksrc + (long)32 * ldk, Kst + 2048 + wave * 512);
  gload16(vsrc, Vst + wave * 512);
  gload16(vsrc + (long)32 * 1024, Vst + 2048 + wave * 512);
#pragma unroll 1
  for (int ch = 0; ch < nchb; ch++) {
    // own t(ch) = 4 loads; younger = 8 stores from compute(ch-1) if it ran
    vmwait((ch >= 1 && ch - 1 < nchw) ? 8 : 0);
    SBAR();
    __builtin_amdgcn_s_barrier();
    SBAR();
    if (ch + 1 < nchb) {
      const bf16* kp = ksrc + (long)(ch + 1) * 64 * ldk;
      const bf16* vp = vsrc + (ch + 1) * 64;
      bf16* kd = Kst + ((ch + 1) & 1) * 4096 + wave * 512;
      bf16* vd = Vst + ((ch + 1) & 1) * 4096 + wave * 512;
      gload16(kp, kd);
      gload16(kp + (long)32 * ldk, kd + 2048);
      gload16(vp, vd);
      gload16(vp + (long)32 * 1024, vd + 2048);
    }
    if (ch < nchw) {
      const int kc = ch * 64;
      const int bo = (ch & 1) * 4096;
      bf16* pw = pst + wave * 2304;
      bf16x8v kf[4][2], vf[4][2];
#pragma unroll
      for (int cc = 0; cc < 4; cc++) {
        const int row = cc * 16 + l16;
#pragma unroll
        for (int ks = 0; ks < 2; ks++) {
          kf[cc][ks] = *reinterpret_cast<const bf16x8v*>(&Kst[bo + row * 64 + sw[ks]]);
          vf[cc][ks] = *reinterpret_cast<const bf16x8v*>(&Vst[bo + row * 64 + sw[ks]]);
        }
      }
      const bool diag = CAUSAL && (ch == nchw - 1);
      __builtin_amdgcn_s_setprio(1);
#pragma unroll
      for (int m = 0; m < 2; m++) {
        f32x4 s[4] = {};
#pragma unroll
        for (int cc = 0; cc < 4; cc++) {
          s[cc] = __builtin_amdgcn_mfma_f32_16x16x32_bf16(kf[cc][0], qB[m][0], s[cc], 0, 0, 0);
          s[cc] = __builtin_amdgcn_mfma_f32_16x16x32_bf16(kf[cc][1], qB[m][1], s[cc], 0, 0, 0);
        }
        if (diag) {
          const int rq = qrel + m * 16 + l16;
#pragma unroll
          for (int cc = 0; cc < 4; cc++)
#pragma unroll
            for (int j = 0; j < 4; j++)
              s[cc][j] = (cc * 16 + lhi * 4 + j <= rq) ? s[cc][j] : -1e30f;
        }
        const int prow = (m * 16 + l16) * 72;
#pragma unroll
        for (int cc = 0; cc < 4; cc++) {
          union { short sh[4]; u32x2 u; } pk;
#pragma unroll
          for (int j = 0; j < 4; j++) pk.sh[j] = f2bs(ex2(s[cc][j]) * il[m]);
          *reinterpret_cast<u32x2*>(&pw[prow + cc * 16 + lhi * 4]) = pk.u;
        }
      }
      // PV from pst
#pragma unroll
      for (int m = 0; m < 2; m++) {
        const int prow = (m * 16 + l16) * 72;
        bf16x8v pa0 = *reinterpret_cast<const bf16x8v*>(&pw[prow + lhi * 8]);
        bf16x8v pa1 = *reinterpret_cast<const bf16x8v*>(&pw[prow + 32 + lhi * 8]);
#pragma unroll
        for (int n = 0; n < 4; n++) {
          pv[m][n] = __builtin_amdgcn_mfma_f32_16x16x32_bf16(pa0, vf[n][0], pv[m][n], 0, 0, 0);
          pv[m][n] = __builtin_amdgcn_mfma_f32_16x16x32_bf16(pa1, vf[n][1], pv[m][n], 0, 0, 0);
        }
      }
      __builtin_amdgcn_s_setprio(0);
      // flush P: 8 nt-stores, each 4 rows x 256B contiguous
#pragma unroll
      for (int f = 0; f < 8; f++) {
        const int row = f * 4 + (lane >> 4);
        u32x2 raw = *reinterpret_cast<const u32x2*>(&pw[row * 72 + (lane & 15) * 4]);
        union { unsigned int u; float fl; } c0, c1, c2, c3;
        c0.u = raw[0] << 16; c1.u = raw[0] & 0xffff0000u;
        c2.u = raw[1] << 16; c3.u = raw[1] & 0xffff0000u;
        f32x4 val = {c0.fl, c1.fl, c2.fl, c3.fl};
        __builtin_nontemporal_store(
            val, reinterpret_cast<f32x4*>(Pg + (long)row * 1024 + kc + (lane & 15) * 4));
      }
    }
  }

  bf16* cb = ctx + (long)(b * 1024 + q0) * 512 + h * 64;
#pragma unroll
  for (int m = 0; m < 2; m++)
#pragma unroll
    for (int n = 0; n < 4; n++)
#pragma unroll
      for (int j = 0; j < 4; j++)
        cb[(long)(m * 16 + lhi * 4 + j) * 512 + n * 16 + l16] = f2b(pv[m][n][j]);
}

template <bool CAUSAL>
__global__ __launch_bounds__(256) void attn_k(
    const bf16* __restrict__ Qm, int ldq, const bf16* __restrict__ Km, int ldk,
    const bf16* __restrict__ vt, float* __restrict__ P, bf16* __restrict__ ctx) {
  __shared__ __align__(16) char smem[51200];
  attn_body<CAUSAL>(blockIdx.x, smem, Qm, ldq, Km, ldk, vt, P, ctx);
}

// merged: blocks 0..511 self-attention, 512..1023 kv2 GEMM (independent work)
__global__ __launch_bounds__(256) void attn_gemm_k(
    const bf16* __restrict__ Qm, int ldq, const bf16* __restrict__ Km, int ldk,
    const bf16* __restrict__ vt, float* __restrict__ P, bf16* __restrict__ ctx,
    const bf16* __restrict__ A, int lda, const bf16* __restrict__ Bt, int ldb,
    bf16* __restrict__ C, int ldc, const float* __restrict__ bias, int K, int tiles_n) {
  __shared__ __align__(16) char smem[51200];
  if (blockIdx.x < 512) {
    attn_body<true>(blockIdx.x, smem, Qm, ldq, Km, ldk, vt, P, ctx);
  } else {
    bf16* sA = (bf16*)smem;
    gemm_body<4, 4, bf16, false>(blockIdx.x - 512, 512, A, lda, Bt, ldb,
                                 C, ldc, bias, K, tiles_n, sA, sA + 8192);
  }
}

// ---------------- GEMM + residual add + LayerNorm fused epilogue ----------------
__global__ __launch_bounds__(512) void gemm_ln_k(
    const bf16* __restrict__ A, int lda, const bf16* __restrict__ Bt,
    const float* __restrict__ bias, const float* __restrict__ resid,
    const float* __restrict__ gamma, const float* __restrict__ beta,
    float* __restrict__ outf, bf16* __restrict__ outb, int K) {
  __shared__ bf16 sA[2][32 * 32];
  __shared__ bf16 sB[2][512 * 32];
  __shared__ float red[2][32][8];
  __shared__ f32x2 mr[32];
  const int tm = blockIdx.x;
  const int tid = threadIdx.x, wave = tid >> 6, lane = tid & 63;
  const int l16 = lane & 15, lhi = lane >> 4;

  const bf16* Asrc = A + (long)(tm * 32 + (tid >> 2)) * lda + (tid & 3) * 8;
  const bf16* Bsrc = Bt + (long)(tid >> 2) * K + (tid & 3) * 8;

  auto stage = [&](int buf, int k0) {
    if (tid < 128) gload16(Asrc + k0, &sA[buf][(tid >> 6) * 512]);
#pragma unroll
    for (int p = 0; p < 4; p++)
      gload16(Bsrc + (long)(p * 128) * K + k0, &sB[buf][p * 4096 + wave * 512]);
  };

  stage(0, 0);
  __syncthreads();

  f32x4 acc[2][4] = {};
  int cur = 0;
  for (int k0 = 0; k0 < K; k0 += 32) {
    if (k0 + 32 < K) stage(cur ^ 1, k0 + 32);
    bf16x8v af[2], bfr[4];
#pragma unroll
    for (int m = 0; m < 2; m++)
      af[m] = *reinterpret_cast<const bf16x8v*>(&sA[cur][(m * 16 + l16) * 32 + lhi * 8]);
#pragma unroll
    for (int n = 0; n < 4; n++)
      bfr[n] = *reinterpret_cast<const bf16x8v*>(&sB[cur][(wave * 64 + n * 16 + l16) * 32 + lhi * 8]);
#pragma unroll
    for (int m = 0; m < 2; m++)
#pragma unroll
      for (int n = 0; n < 4; n++)
        acc[m][n] = __builtin_amdgcn_mfma_f32_16x16x32_bf16(af[m], bfr[n], acc[m][n], 0, 0, 0);
    if (k0 + 32 < K) {
      __syncthreads();
      cur ^= 1;
    }
  }

  float bv[4], gm[4], bt[4];
#pragma unroll
  for (int n = 0; n < 4; n++) {
    const int gc = wave * 64 + n * 16 + l16;
    bv[n] = bias[gc]; gm[n] = gamma[gc]; bt[n] = beta[gc];
  }
  float v[2][4][4], rs[2][4], rq[2][4];
#pragma unroll
  for (int m = 0; m < 2; m++)
#pragma unroll
    for (int j = 0; j < 4; j++) { rs[m][j] = 0.f; rq[m][j] = 0.f; }
#pragma unroll
  for (int m = 0; m < 2; m++) {
#pragma unroll
    for (int j = 0; j < 4; j++) {
      const long grow = tm * 32 + m * 16 + lhi * 4 + j;
#pragma unroll
      for (int n = 0; n < 4; n++) {
        const int gc = wave * 64 + n * 16 + l16;
        const float val = acc[m][n][j] + bv[n] + resid[grow * 512 + gc];
        v[m][n][j] = val;
        rs[m][j] += val;
        rq[m][j] += val * val;
      }
    }
  }
#pragma unroll
  for (int m = 0; m < 2; m++)
#pragma unroll
    for (int j = 0; j < 4; j++)
#pragma unroll
      for (int off = 1; off <= 8; off <<= 1) {
        rs[m][j] += __shfl_xor(rs[m][j], off);
        rq[m][j] += __shfl_xor(rq[m][j], off);
      }
  if (l16 == 0) {
#pragma unroll
    for (int m = 0; m < 2; m++)
#pragma unroll
      for (int j = 0; j < 4; j++) {
        red[0][m * 16 + lhi * 4 + j][wave] = rs[m][j];
        red[1][m * 16 + lhi * 4 + j][wave] = rq[m][j];
      }
  }
  __syncthreads();
  if (tid < 32) {
    float s = 0.f, q = 0.f;
#pragma unroll
    for (int w = 0; w < 8; w++) { s += red[0][tid][w]; q += red[1][tid][w]; }
    const float mean = s * (1.f / 512.f);
    const float var = q * (1.f / 512.f) - mean * mean;
    f32x2 o = {mean, rsqrtf(var + 1e-5f)};
    mr[tid] = o;
  }
  __syncthreads();
#pragma unroll
  for (int m = 0; m < 2; m++) {
#pragma unroll
    for (int j = 0; j < 4; j++) {
      const int row = m * 16 + lhi * 4 + j;
      const f32x2 mrv = mr[row];
      const long grow = tm * 32 + row;
#pragma unroll
      for (int n = 0; n < 4; n++) {
        const int gc = wave * 64 + n * 16 + l16;
        const float o = (v[m][n][j] - mrv[0]) * mrv[1] * gm[n] + bt[n];
        outf[grow * 512 + gc] = o;
        if (outb) outb[grow * 512 + gc] = f2b(o);
      }
    }
  }
}

extern "C" void kernel_launch(void* const* d_in, const int* in_sizes, int n_in,
                              void* d_out, int out_size, void* d_ws, size_t ws_size,
                              hipStream_t stream) {
  const float* x = (const float*)d_in[0];
  const float* enc = (const float*)d_in[1];
  const float* wq1 = (const float*)d_in[4];  const float* bq1 = (const float*)d_in[5];
  const float* wk1 = (const float*)d_in[6];  const float* bk1 = (const float*)d_in[7];
  const float* wv1 = (const float*)d_in[8];  const float* bv1 = (const float*)d_in[9];
  const float* wo1 = (const float*)d_in[10]; const float* bo1 = (const float*)d_in[11];
  const float* wq2 = (const float*)d_in[12]; const float* bq2 = (const float*)d_in[13];
  const float* wk2 = (const float*)d_in[14]; const float* bk2 = (const float*)d_in[15];
  const float* wv2 = (const float*)d_in[16]; const float* bv2 = (const float*)d_in[17];
  const float* wo2 = (const float*)d_in[18]; const float* bo2 = (const float*)d_in[19];
  const float* wff1 = (const float*)d_in[20]; const float* bff1 = (const float*)d_in[21];
  const float* wff2 = (const float*)d_in[22]; const float* bff2 = (const float*)d_in[23];
  const float* gamma1 = (const float*)d_in[24]; const float* beta1 = (const float*)d_in[25];
  const float* gamma2 = (const float*)d_in[26]; const float* beta2 = (const float*)d_in[27];
  const float* gamma3 = (const float*)d_in[28]; const float* beta3 = (const float*)d_in[29];

  float* out3 = (float*)d_out;
  float* sa_w = out3 + (long)8 * 1024 * 512;
  float* ca_w = sa_w + (long)64 * 1024 * 1024;

  char* w = (char*)d_ws;
  auto alloc = [&](long bytes) { char* p = w; w += (bytes + 255) & ~255L; return p; };
  bf16* xb     = (bf16*)alloc(8192L * 512 * 2);
  bf16* encb   = (bf16*)alloc(8192L * 512 * 2);
  bf16* wqkv1t = (bf16*)alloc(1536L * 512 * 2);
  bf16* wo1t   = (bf16*)alloc(512L * 512 * 2);
  bf16* wq2t   = (bf16*)alloc(512L * 512 * 2);
  bf16* wkv2t  = (bf16*)alloc(1024L * 512 * 2);
  bf16* wo2t   = (bf16*)alloc(512L * 512 * 2);
  bf16* wff1t  = (bf16*)alloc(2048L * 512 * 2);
  bf16* wff2t  = (bf16*)alloc(512L * 2048 * 2);
  float* bcat  = (float*)alloc(3072L * 4);
  bf16* qkv    = (bf16*)alloc(8192L * 1536 * 2);
  bf16* q2b    = (bf16*)alloc(8192L * 512 * 2);
  bf16* kv2    = (bf16*)alloc(8192L * 1024 * 2);
  bf16* vt     = (bf16*)alloc(64L * 64 * 1024 * 2);
  bf16* vt2    = (bf16*)alloc(64L * 64 * 1024 * 2);
  bf16* ctx    = (bf16*)alloc(8192L * 512 * 2);
  float* out1  = (float*)alloc(8192L * 512 * 4);
  bf16* out1b  = (bf16*)alloc(8192L * 512 * 2);
  float* out2  = (float*)alloc(8192L * 512 * 4);
  bf16* out2b  = (bf16*)alloc(8192L * 512 * 2);
  bf16* ffh    = qkv;  // alias: qkv + q2b dead by FFN; spans 32MB

  // ---- prep (1 kernel) ----
  PrepPack pp;
  pp.x = x; pp.enc = enc; pp.xb = xb; pp.encb = encb;
  pp.d[0] = {wq1,  wqkv1t,               512,  512,  0,    QSCL};
  pp.d[1] = {wk1,  wqkv1t + 512L * 512,  512,  512,  256,  1.f};
  pp.d[2] = {wv1,  wqkv1t + 1024L * 512, 512,  512,  512,  1.f};
  pp.d[3] = {wo1,  wo1t,                 512,  512,  768,  1.f};
  pp.d[4] = {wq2,  wq2t,                 512,  512,  1024, QSCL};
  pp.d[5] = {wk2,  wkv2t,                512,  512,  1280, 1.f};
  pp.d[6] = {wv2,  wkv2t + 512L * 512,   512,  512,  1536, 1.f};
  pp.d[7] = {wo2,  wo2t,                 512,  512,  1792, 1.f};
  pp.d[8] = {wff1, wff1t,                512,  2048, 2048, 1.f};
  pp.d[9] = {wff2, wff2t,                2048, 512,  3072, 1.f};
  pp.bsrc[0] = bq1; pp.bsrc[1] = bk1; pp.bsrc[2] = bv1;
  pp.bsrc[3] = bk2; pp.bsrc[4] = bv2; pp.bsrc[5] = bq2;
  pp.bscl[0] = QSCL; pp.bscl[1] = 1.f; pp.bscl[2] = 1.f;
  pp.bscl[3] = 1.f;  pp.bscl[4] = 1.f; pp.bscl[5] = QSCL;
  pp.bdst = bcat;
  prep_k<<<12294, 256, 0, stream>>>(pp);

  // ================= self attention (+ overlapped cross K/V projection) ========
  gemm_gl_k<4, 4, bf16, false><<<768, 256, 0, stream>>>(
      xb, 512, wqkv1t, 512, qkv, 1536, bcat, 512, 12);
  transpose_v_bh_k<<<dim3(2, 32, 64), 256, 0, stream>>>(qkv + 1024, 1536, vt);
  attn_gemm_k<<<1024, 256, 0, stream>>>(
      qkv, 1536, qkv + 512, 1536, vt, sa_w, ctx,
      encb, 512, wkv2t, 512, kv2, 1024, bcat + 1536, 512, 8);
  gemm_ln_k<<<256, 512, 0, stream>>>(
      ctx, 512, wo1t, bo1, x, gamma1, beta1, out1, out1b, 512);

  // ================= cross attention =================
  q2vt_k<<<4608, 256, 0, stream>>>(out1b, wq2t, q2b, bcat + 2560, kv2 + 512, vt2);
  attn_k<false><<<512, 256, 0, stream>>>(
      q2b, 512, kv2, 1024, vt2, ca_w, ctx);
  gemm_ln_k<<<256, 512, 0, stream>>>(
      ctx, 512, wo2t, bo2, out1, gamma2, beta2, out2, out2b, 512);

  // ================= FFN =================
  gemm_gl_k<4, 4, bf16, true><<<1024, 256, 0, stream>>>(
      out2b, 512, wff1t, 512, ffh, 2048, bff1, 512, 16);
  gemm_ln_k<<<256, 512, 0, stream>>>(
      ffh, 2048, wff2t, bff2, out2, gamma3, beta3, out3, nullptr, 2048);
}

// Round 10
// 370.288 us; speedup vs baseline: 1.0663x; 1.0663x over previous
//
#include <hip/hip_runtime.h>
#include <hip/hip_bf16.h>

// DecoderLayer: B=8, T=S=1024, D=512, H=8, depth=64, F=2048. fp32 in/out.
// Outputs (concat in d_out): out3 [8,1024,512], sa_w [64,1024,1024], ca_w [64,1024,1024].
// Round 10: attn reverted to round-8 (KVBLK=32 triple-buffer counted-vmcnt, best
// measured). V-transpose fused into producing GEMM epilogues (vt/vt2 written
// directly, V cols of qkv/kv2 skipped). LayerNorm fp32 outputs dropped - bf16
// residual chain (out1b/out2b). 9 nodes.

using bf16 = __hip_bfloat16;
typedef __attribute__((ext_vector_type(8))) short bf16x8v;
typedef __attribute__((ext_vector_type(4))) float f32x4;
typedef __attribute__((ext_vector_type(2))) float f32x2;
typedef __attribute__((ext_vector_type(2))) unsigned int u32x2;

#define DEVI __device__ __forceinline__

// 0.125 (1/sqrt(depth)) * log2(e): logits computed directly in exp2 units.
#define QSCL 0.18033688011112042f

DEVI short f2bs(float f) {
  bf16 h = __float2bfloat16(f);
  return *reinterpret_cast<short*>(&h);
}
DEVI bf16 f2b(float f) { return __float2bfloat16(f); }
DEVI float ex2(float x) { return __builtin_amdgcn_exp2f(x); }
DEVI float ldf(const float* p) { return *p; }
DEVI float ldf(const bf16* p) { return __bfloat162float(*p); }

DEVI void gload16(const bf16* g, bf16* l) {
  __builtin_amdgcn_global_load_lds(
      (const __attribute__((address_space(1))) void*)g,
      (__attribute__((address_space(3))) void*)l, 16, 0, 0);
}

// wave-uniform counted vmcnt wait (immediates only)
DEVI void vmwait(int n) {
  if (n == 0)       asm volatile("s_waitcnt vmcnt(0)" ::: "memory");
  else if (n == 1)  asm volatile("s_waitcnt vmcnt(1)" ::: "memory");
  else if (n == 2)  asm volatile("s_waitcnt vmcnt(2)" ::: "memory");
  else if (n == 4)  asm volatile("s_waitcnt vmcnt(4)" ::: "memory");
  else if (n == 6)  asm volatile("s_waitcnt vmcnt(6)" ::: "memory");
  else if (n == 8)  asm volatile("s_waitcnt vmcnt(8)" ::: "memory");
  else              asm volatile("s_waitcnt vmcnt(10)" ::: "memory");
}
#define SBAR() __builtin_amdgcn_sched_barrier(0)

// ---------------- fused prep: casts + weight transposes + bias concat ----------
struct WDesc { const float* src; bf16* dst; int K; int N; int toff; float scl; };
struct PrepPack {
  const float* x; const float* enc; bf16* xb; bf16* encb;
  WDesc d[10];
  const float* bsrc[6]; float bscl[6]; float* bdst;
};

__global__ __launch_bounds__(256) void prep_k(PrepPack p) {
  const int bid = blockIdx.x;
  if (bid < 8192) {
    const float* s = (bid < 4096) ? p.x : p.enc;
    bf16* d = (bid < 4096) ? p.xb : p.encb;
    long i = ((long)(bid & 4095) * 256 + threadIdx.x) * 4;
    f32x4 v = *reinterpret_cast<const f32x4*>(s + i);
    union { short sh[4]; long l; } u;
    u.sh[0] = f2bs(v[0]); u.sh[1] = f2bs(v[1]); u.sh[2] = f2bs(v[2]); u.sh[3] = f2bs(v[3]);
    *reinterpret_cast<long*>(d + i) = u.l;
    return;
  }
  if (bid < 12288) {
    const int t = bid - 8192;
    int wi = 0;
#pragma unroll
    for (int i = 1; i < 10; i++)
      if (t >= p.d[i].toff) wi = i;
    const WDesc d = p.d[wi];
    const int lt = t - d.toff;
    const int nx = d.N >> 5;
    const int n0 = (lt % nx) * 32, k0 = (lt / nx) * 32;
    __shared__ float tile[32][33];
    const int tx = threadIdx.x & 31, ty = threadIdx.x >> 5;
#pragma unroll
    for (int i = 0; i < 32; i += 8)
      tile[ty + i][tx] = d.src[(long)(k0 + ty + i) * d.N + n0 + tx] * d.scl;
    __syncthreads();
#pragma unroll
    for (int i = 0; i < 32; i += 8)
      d.dst[(long)(n0 + ty + i) * d.K + k0 + tx] = f2b(tile[tx][ty + i]);
    return;
  }
  const int i = bid - 12288;
  const int e = threadIdx.x * 2;
  f32x2 v = *reinterpret_cast<const f32x2*>(p.bsrc[i] + e);
  v[0] *= p.bscl[i]; v[1] *= p.bscl[i];
  *reinterpret_cast<f32x2*>(p.bdst + i * 512 + e) = v;
}

// ---------------- GEMM body (shared) ------------
// VTOUT: output columns >= vcol0 are per-(b,h) V heads; write them transposed
// into vtout[bh][d][s] (bf16x4 runs over s) instead of C.
template <int FM, int FN, typename TC, bool RELU, bool VTOUT>
DEVI void gemm_body(int bid, int nblocks,
                    const bf16* __restrict__ A, int lda,
                    const bf16* __restrict__ Bt, int ldb,
                    TC* __restrict__ C, int ldc,
                    const float* __restrict__ bias, int K, int tiles_n,
                    bf16* sA, bf16* sB,
                    bf16* __restrict__ vtout, int vcol0) {
  constexpr int BM = 32 * FM, BN = 32 * FN;
  const int tm8 = (nblocks / tiles_n) >> 3;
  const int r8 = bid >> 3;
  const int tm = (bid & 7) + ((r8 % tm8) << 3);
  const int tn = r8 / tm8;
  const int tid = threadIdx.x, wave = tid >> 6, lane = tid & 63;
  const int wr = wave >> 1, wc = wave & 1;
  const int l16 = lane & 15, lhi = lane >> 4;
  const int srow = lane >> 2, scol = (lane & 3) * 8;

  const bf16* Ab = A + (long)(tm * BM + wave * (BM / 4) + srow) * lda + scol;
  const bf16* Bb = Bt + (long)(tn * BN + wave * (BN / 4) + srow) * ldb + scol;

  auto stage = [&](int buf, int k0) {
#pragma unroll
    for (int i = 0; i < BM / 64; i++)
      gload16(Ab + (long)(i * 16) * lda + k0, sA + buf * BM * 32 + (wave * (BM / 4) + i * 16) * 32);
#pragma unroll
    for (int i = 0; i < BN / 64; i++)
      gload16(Bb + (long)(i * 16) * ldb + k0, sB + buf * BN * 32 + (wave * (BN / 4) + i * 16) * 32);
  };

  stage(0, 0);
  __syncthreads();

  f32x4 acc[FM][FN] = {};
  int cur = 0;
  for (int k0 = 0; k0 < K; k0 += 32) {
    if (k0 + 32 < K) stage(cur ^ 1, k0 + 32);
    bf16x8v af[FM], bfr[FN];
#pragma unroll
    for (int m = 0; m < FM; m++)
      af[m] = *reinterpret_cast<const bf16x8v*>(
          sA + cur * BM * 32 + (wr * 16 * FM + m * 16 + l16) * 32 + lhi * 8);
#pragma unroll
    for (int n = 0; n < FN; n++)
      bfr[n] = *reinterpret_cast<const bf16x8v*>(
          sB + cur * BN * 32 + (wc * 16 * FN + n * 16 + l16) * 32 + lhi * 8);
#pragma unroll
    for (int m = 0; m < FM; m++)
#pragma unroll
      for (int n = 0; n < FN; n++)
        acc[m][n] = __builtin_amdgcn_mfma_f32_16x16x32_bf16(af[m], bfr[n], acc[m][n], 0, 0, 0);
    if (k0 + 32 < K) {
      __syncthreads();
      cur ^= 1;
    }
  }

#pragma unroll
  for (int m = 0; m < FM; m++) {
    const int gr0 = tm * BM + wr * 16 * FM + m * 16 + lhi * 4;
#pragma unroll
    for (int n = 0; n < FN; n++) {
      const int gc = tn * BN + wc * 16 * FN + n * 16 + l16;
      const float bv = bias ? bias[gc] : 0.f;
      if (VTOUT && gc >= vcol0) {
        // V head: write transposed to vt[bh][d][s0..s0+3], skip C
        const int vc = gc - vcol0;
        bf16* vdst = vtout + ((long)(((gr0 >> 10) << 3) + (vc >> 6)) << 16)
                           + ((long)(vc & 63) << 10) + (gr0 & 1023);
        union { short sh[4]; u32x2 u2; } pk;
#pragma unroll
        for (int j = 0; j < 4; j++) pk.sh[j] = f2bs(acc[m][n][j] + bv);
        *reinterpret_cast<u32x2*>(vdst) = pk.u2;
      } else {
#pragma unroll
        for (int j = 0; j < 4; j++) {
          float v = acc[m][n][j] + bv;
          if (RELU) v = fmaxf(v, 0.f);
          if constexpr (sizeof(TC) == 4)
            C[(long)(gr0 + j) * ldc + gc] = v;
          else
            C[(long)(gr0 + j) * ldc + gc] = f2b(v);
        }
      }
    }
  }
}

template <int FM, int FN, typename TC, bool RELU>
__global__ __launch_bounds__(256) void gemm_gl_k(
    const bf16* __restrict__ A, int lda, const bf16* __restrict__ Bt, int ldb,
    TC* __restrict__ C, int ldc, const float* __restrict__ bias, int K, int tiles_n) {
  __shared__ bf16 sA[2 * 32 * FM * 32];
  __shared__ bf16 sB[2 * 32 * FN * 32];
  gemm_body<FM, FN, TC, RELU, false>(blockIdx.x, gridDim.x, A, lda, Bt, ldb, C, ldc,
                                     bias, K, tiles_n, sA, sB, nullptr, 0);
}

// qkv GEMM with fused V-transpose output
__global__ __launch_bounds__(256) void gemm_qkv_k(
    const bf16* __restrict__ A, const bf16* __restrict__ Bt, bf16* __restrict__ C,
    const float* __restrict__ bias, bf16* __restrict__ vt) {
  __shared__ bf16 sA[2 * 128 * 32];
  __shared__ bf16 sB[2 * 128 * 32];
  gemm_body<4, 4, bf16, false, true>(blockIdx.x, gridDim.x, A, 512, Bt, 512, C, 1536,
                                     bias, 512, 12, sA, sB, vt, 1024);
}

// ---------------- attention body: counted-vmcnt pipelined 2-pass flash ----------
// (round-8 verified version) LDS 34816 B: Kst[3][2048] | Vst[3][2048] | pst[4][1280]
template <bool CAUSAL>
DEVI void attn_body(int bid, char* smem,
                    const bf16* __restrict__ Qm, int ldq,
                    const bf16* __restrict__ Km, int ldk,
                    const bf16* __restrict__ vt,
                    float* __restrict__ P, bf16* __restrict__ ctx) {
  bf16* Kst = (bf16*)smem;      // 3 x 2048 elems
  bf16* Vst = Kst + 3 * 2048;   // 3 x 2048
  bf16* pst = Vst + 3 * 2048;   // 4 x 1280
  const int bh = bid & 63;
  const int g = bid >> 6;
  const int qx = CAUSAL ? ((g < 4) ? g : 11 - g) : g;  // anti-correlated pairs
  const int b = bh >> 3, h = bh & 7;
  const int tid = threadIdx.x, wave = tid >> 6, lane = tid & 63;
  const int l16 = lane & 15, lhi = lane >> 4;
  const int q0 = qx * 128 + wave * 32;
  const bf16* Qb = Qm + (long)(b * 1024 + q0) * ldq + h * 64;
  const bf16* Kb = Km + (long)b * 1024 * ldk + h * 64;
  const bf16* Vb = vt + (long)bh * 64 * 1024;

  const int nun = CAUSAL ? (q0 >> 5) : 32;
  const int nchw = CAUSAL ? nun + 1 : 32;
  const int nchb = CAUSAL ? qx * 4 + 4 : 32;

  const bf16* ksrc = Kb + (long)(tid >> 3) * ldk + ((tid & 7) ^ ((tid >> 3) & 7)) * 8;
  const bf16* vsrc = Vb + (long)(tid >> 2) * 1024 + ((tid & 3) ^ ((tid >> 2) & 3)) * 8;

  int kfo[2][2];
#pragma unroll
  for (int cc = 0; cc < 2; cc++) {
    const int r = cc * 16 + l16;
#pragma unroll
    for (int ks = 0; ks < 2; ks++)
      kfo[cc][ks] = r * 64 + (((ks * 64 + lhi * 16) ^ ((r & 7) << 4)) >> 1);
  }
  int vfo[4];
#pragma unroll
  for (int n = 0; n < 4; n++) {
    const int r = n * 16 + l16;
    vfo[n] = r * 32 + (((lhi * 16) ^ ((r & 3) << 4)) >> 1);
  }

  bf16x8v qB[2][2];
#pragma unroll
  for (int m = 0; m < 2; m++)
#pragma unroll
    for (int ks = 0; ks < 2; ks++)
      qB[m][ks] = *reinterpret_cast<const bf16x8v*>(
          Qb + (long)(m * 16 + l16) * ldq + ks * 32 + lhi * 8);

  float ll[2] = {0.f, 0.f};

  // ================ pass 1: l-sum only (no max), K triple-buffered ================
  gload16(ksrc, Kst + wave * 512);
  gload16(ksrc + (long)32 * ldk, Kst + 2048 + wave * 512);
#pragma unroll 1
  for (int ch = 0; ch < nchb; ch++) {
    if (ch + 1 < nchb) vmwait(1); else vmwait(0);
    SBAR();
    __builtin_amdgcn_s_barrier();
    SBAR();
    if (ch + 2 < nchb)
      gload16(ksrc + (long)(ch + 2) * 32 * ldk, Kst + ((ch + 2) % 3) * 2048 + wave * 512);
    if (ch < nchw) {
      const int bo = (ch % 3) * 2048;
      bf16x8v kf[2][2];
#pragma unroll
      for (int cc = 0; cc < 2; cc++)
#pragma unroll
        for (int ks = 0; ks < 2; ks++)
          kf[cc][ks] = *reinterpret_cast<const bf16x8v*>(&Kst[bo + kfo[cc][ks]]);
      const bool diag = CAUSAL && (ch == nun);
#pragma unroll
      for (int m = 0; m < 2; m++) {
        f32x4 s0 = {}, s1 = {};
        s0 = __builtin_amdgcn_mfma_f32_16x16x32_bf16(kf[0][0], qB[m][0], s0, 0, 0, 0);
        s0 = __builtin_amdgcn_mfma_f32_16x16x32_bf16(kf[0][1], qB[m][1], s0, 0, 0, 0);
        s1 = __builtin_amdgcn_mfma_f32_16x16x32_bf16(kf[1][0], qB[m][0], s1, 0, 0, 0);
        s1 = __builtin_amdgcn_mfma_f32_16x16x32_bf16(kf[1][1], qB[m][1], s1, 0, 0, 0);
        if (diag) {
          const int rq = m * 16 + l16;
#pragma unroll
          for (int j = 0; j < 4; j++) {
            s0[j] = (lhi * 4 + j <= rq) ? s0[j] : -1e30f;   // exp2 -> 0 exactly
            s1[j] = (16 + lhi * 4 + j <= rq) ? s1[j] : -1e30f;
          }
        }
        float sum = 0.f;
#pragma unroll
        for (int j = 0; j < 4; j++) sum += ex2(s0[j]) + ex2(s1[j]);
        ll[m] += sum;
      }
    }
  }
  __syncthreads();  // pass boundary

  float il[2];
#pragma unroll
  for (int m = 0; m < 2; m++) {
    float lo = ll[m];
    lo += __shfl_xor(lo, 16);
    lo += __shfl_xor(lo, 32);
    il[m] = 1.f / lo;
  }

  // ================ pass 2: P write + PV, K+V triple-buffered ================
  f32x4 pv[2][4] = {};
  float* Pg = P + (long)bh * 1024 * 1024 + (long)q0 * 1024;
  gload16(ksrc, Kst + wave * 512);
  gload16(vsrc, Vst + wave * 512);
  gload16(ksrc + (long)32 * ldk, Kst + 2048 + wave * 512);
  gload16(vsrc + 32, Vst + 2048 + wave * 512);
#pragma unroll 1
  for (int ch = 0; ch < nchb; ch++) {
    const int Sa = (ch >= 2 && ch - 2 < nchw) ? 4 : 0;
    const int Lr = (ch + 1 < nchb) ? 2 : 0;
    const int Sb = (ch >= 1 && ch - 1 < nchw) ? 4 : 0;
    vmwait(Sa + Lr + Sb);
    SBAR();
    __builtin_amdgcn_s_barrier();
    SBAR();
    if (ch + 2 < nchb) {
      gload16(ksrc + (long)(ch + 2) * 32 * ldk, Kst + ((ch + 2) % 3) * 2048 + wave * 512);
      gload16(vsrc + (ch + 2) * 32, Vst + ((ch + 2) % 3) * 2048 + wave * 512);
    }
    if (ch < nchw) {
      const int kc = ch * 32;
      const int bo = (ch % 3) * 2048;
      bf16x8v kf[2][2], vf[4];
#pragma unroll
      for (int cc = 0; cc < 2; cc++)
#pragma unroll
        for (int ks = 0; ks < 2; ks++)
          kf[cc][ks] = *reinterpret_cast<const bf16x8v*>(&Kst[bo + kfo[cc][ks]]);
#pragma unroll
      for (int n = 0; n < 4; n++)
        vf[n] = *reinterpret_cast<const bf16x8v*>(&Vst[bo + vfo[n]]);
      const bool diag = CAUSAL && (ch == nun);
#pragma unroll
      for (int m = 0; m < 2; m++) {
        f32x4 s0 = {}, s1 = {};
        s0 = __builtin_amdgcn_mfma_f32_16x16x32_bf16(kf[0][0], qB[m][0], s0, 0, 0, 0);
        s0 = __builtin_amdgcn_mfma_f32_16x16x32_bf16(kf[0][1], qB[m][1], s0, 0, 0, 0);
        s1 = __builtin_amdgcn_mfma_f32_16x16x32_bf16(kf[1][0], qB[m][0], s1, 0, 0, 0);
        s1 = __builtin_amdgcn_mfma_f32_16x16x32_bf16(kf[1][1], qB[m][1], s1, 0, 0, 0);
        if (diag) {
          const int rq = m * 16 + l16;
#pragma unroll
          for (int j = 0; j < 4; j++) {
            s0[j] = (lhi * 4 + j <= rq) ? s0[j] : -1e30f;
            s1[j] = (16 + lhi * 4 + j <= rq) ? s1[j] : -1e30f;
          }
        }
        f32x4 p0, p1;
#pragma unroll
        for (int j = 0; j < 4; j++) {
          p0[j] = ex2(s0[j]) * il[m];
          p1[j] = ex2(s1[j]) * il[m];
        }
        const int prow = (m * 16 + l16) * 40;
        union { short s[4]; u32x2 u; } pk0, pk1;
#pragma unroll
        for (int j = 0; j < 4; j++) { pk0.s[j] = f2bs(p0[j]); pk1.s[j] = f2bs(p1[j]); }
        *reinterpret_cast<u32x2*>(&pst[wave * 1280 + prow + lhi * 4]) = pk0.u;
        *reinterpret_cast<u32x2*>(&pst[wave * 1280 + prow + 16 + lhi * 4]) = pk1.u;
      }
#pragma unroll
      for (int m = 0; m < 2; m++) {
        bf16x8v pa = *reinterpret_cast<const bf16x8v*>(
            &pst[wave * 1280 + (m * 16 + l16) * 40 + lhi * 8]);
#pragma unroll
        for (int n = 0; n < 4; n++)
          pv[m][n] = __builtin_amdgcn_mfma_f32_16x16x32_bf16(pa, vf[n], pv[m][n], 0, 0, 0);
      }
      // flush P from pst (bf16 -> f32 bitshift): 4 nt-stores, 8 rows x 128B each
#pragma unroll
      for (int f = 0; f < 4; f++) {
        const int row = f * 8 + (lane >> 3);
        u32x2 raw = *reinterpret_cast<const u32x2*>(
            &pst[wave * 1280 + row * 40 + (lane & 7) * 4]);
        union { unsigned int u; float fl; } c0, c1, c2, c3;
        c0.u = raw[0] << 16; c1.u = raw[0] & 0xffff0000u;
        c2.u = raw[1] << 16; c3.u = raw[1] & 0xffff0000u;
        f32x4 val = {c0.fl, c1.fl, c2.fl, c3.fl};
        __builtin_nontemporal_store(
            val, reinterpret_cast<f32x4*>(Pg + (long)row * 1024 + kc + (lane & 7) * 4));
      }
    }
  }

  bf16* cb = ctx + (long)(b * 1024 + q0) * 512 + h * 64;
#pragma unroll
  for (int m = 0; m < 2; m++)
#pragma unroll
    for (int n = 0; n < 4; n++)
#pragma unroll
      for (int j = 0; j < 4; j++)
        cb[(long)(m * 16 + lhi * 4 + j) * 512 + n * 16 + l16] = f2b(pv[m][n][j]);
}

template <bool CAUSAL>
__global__ __launch_bounds__(256) void attn_k(
    const bf16* __restrict__ Qm, int ldq, const bf16* __restrict__ Km, int ldk,
    const bf16* __restrict__ vt, float* __restrict__ P, bf16* __restrict__ ctx) {
  __shared__ __align__(16) char smem[34816];
  attn_body<CAUSAL>(blockIdx.x, smem, Qm, ldq, Km, ldk, vt, P, ctx);
}

// merged: blocks 0..511 self-attention, 512..1023 kv2 GEMM (+fused vt2 output)
__global__ __launch_bounds__(256) void attn_gemm_k(
    const bf16* __restrict__ Qm, int ldq, const bf16* __restrict__ Km, int ldk,
    const bf16* __restrict__ vt, float* __restrict__ P, bf16* __restrict__ ctx,
    const bf16* __restrict__ A, int lda, const bf16* __restrict__ Bt, int ldb,
    bf16* __restrict__ C, int ldc, const float* __restrict__ bias, int K, int tiles_n,
    bf16* __restrict__ vt2) {
  __shared__ __align__(16) char smem[34816];
  if (blockIdx.x < 512) {
    attn_body<true>(blockIdx.x, smem, Qm, ldq, Km, ldk, vt, P, ctx);
  } else {
    bf16* sA = (bf16*)smem;
    gemm_body<4, 4, bf16, false, true>(blockIdx.x - 512, 512, A, lda, Bt, ldb,
                                       C, ldc, bias, K, tiles_n, sA, sA + 8192,
                                       vt2, 512);
  }
}

// ---------------- GEMM + residual add + LayerNorm fused epilogue ----------------
// resid may be fp32 or bf16 (TR).
template <typename TR>
__global__ __launch_bounds__(512) void gemm_ln_k(
    const bf16* __restrict__ A, int lda, const bf16* __restrict__ Bt,
    const float* __restrict__ bias, const TR* __restrict__ resid,
    const float* __restrict__ gamma, const float* __restrict__ beta,
    float* __restrict__ outf, bf16* __restrict__ outb, int K) {
  __shared__ bf16 sA[2][32 * 32];
  __shared__ bf16 sB[2][512 * 32];
  __shared__ float red[2][32][8];
  __shared__ f32x2 mr[32];
  const int tm = blockIdx.x;
  const int tid = threadIdx.x, wave = tid >> 6, lane = tid & 63;
  const int l16 = lane & 15, lhi = lane >> 4;

  const bf16* Asrc = A + (long)(tm * 32 + (tid >> 2)) * lda + (tid & 3) * 8;
  const bf16* Bsrc = Bt + (long)(tid >> 2) * K + (tid & 3) * 8;

  auto stage = [&](int buf, int k0) {
    if (tid < 128) gload16(Asrc + k0, &sA[buf][(tid >> 6) * 512]);
#pragma unroll
    for (int p = 0; p < 4; p++)
      gload16(Bsrc + (long)(p * 128) * K + k0, &sB[buf][p * 4096 + wave * 512]);
  };

  stage(0, 0);
  __syncthreads();

  f32x4 acc[2][4] = {};
  int cur = 0;
  for (int k0 = 0; k0 < K; k0 += 32) {
    if (k0 + 32 < K) stage(cur ^ 1, k0 + 32);
    bf16x8v af[2], bfr[4];
#pragma unroll
    for (int m = 0; m < 2; m++)
      af[m] = *reinterpret_cast<const bf16x8v*>(&sA[cur][(m * 16 + l16) * 32 + lhi * 8]);
#pragma unroll
    for (int n = 0; n < 4; n++)
      bfr[n] = *reinterpret_cast<const bf16x8v*>(&sB[cur][(wave * 64 + n * 16 + l16) * 32 + lhi * 8]);
#pragma unroll
    for (int m = 0; m < 2; m++)
#pragma unroll
      for (int n = 0; n < 4; n++)
        acc[m][n] = __builtin_amdgcn_mfma_f32_16x16x32_bf16(af[m], bfr[n], acc[m][n], 0, 0, 0);
    if (k0 + 32 < K) {
      __syncthreads();
      cur ^= 1;
    }
  }

  float bv[4], gm[4], bt[4];
#pragma unroll
  for (int n = 0; n < 4; n++) {
    const int gc = wave * 64 + n * 16 + l16;
    bv[n] = bias[gc]; gm[n] = gamma[gc]; bt[n] = beta[gc];
  }
  float v[2][4][4], rs[2][4], rq[2][4];
#pragma unroll
  for (int m = 0; m < 2; m++)
#pragma unroll
    for (int j = 0; j < 4; j++) { rs[m][j] = 0.f; rq[m][j] = 0.f; }
#pragma unroll
  for (int m = 0; m < 2; m++) {
#pragma unroll
    for (int j = 0; j < 4; j++) {
      const long grow = tm * 32 + m * 16 + lhi * 4 + j;
#pragma unroll
      for (int n = 0; n < 4; n++) {
        const int gc = wave * 64 + n * 16 + l16;
        const float val = acc[m][n][j] + bv[n] + ldf(resid + grow * 512 + gc);
        v[m][n][j] = val;
        rs[m][j] += val;
        rq[m][j] += val * val;
      }
    }
  }
#pragma unroll
  for (int m = 0; m < 2; m++)
#pragma unroll
    for (int j = 0; j < 4; j++)
#pragma unroll
      for (int off = 1; off <= 8; off <<= 1) {
        rs[m][j] += __shfl_xor(rs[m][j], off);
        rq[m][j] += __shfl_xor(rq[m][j], off);
      }
  if (l16 == 0) {
#pragma unroll
    for (int m = 0; m < 2; m++)
#pragma unroll
      for (int j = 0; j < 4; j++) {
        red[0][m * 16 + lhi * 4 + j][wave] = rs[m][j];
        red[1][m * 16 + lhi * 4 + j][wave] = rq[m][j];
      }
  }
  __syncthreads();
  if (tid < 32) {
    float s = 0.f, q = 0.f;
#pragma unroll
    for (int w = 0; w < 8; w++) { s += red[0][tid][w]; q += red[1][tid][w]; }
    const float mean = s * (1.f / 512.f);
    const float var = q * (1.f / 512.f) - mean * mean;
    f32x2 o = {mean, rsqrtf(var + 1e-5f)};
    mr[tid] = o;
  }
  __syncthreads();
#pragma unroll
  for (int m = 0; m < 2; m++) {
#pragma unroll
    for (int j = 0; j < 4; j++) {
      const int row = m * 16 + lhi * 4 + j;
      const f32x2 mrv = mr[row];
      const long grow = tm * 32 + row;
#pragma unroll
      for (int n = 0; n < 4; n++) {
        const int gc = wave * 64 + n * 16 + l16;
        const float o = (v[m][n][j] - mrv[0]) * mrv[1] * gm[n] + bt[n];
        if (outf) outf[grow * 512 + gc] = o;
        if (outb) outb[grow * 512 + gc] = f2b(o);
      }
    }
  }
}

extern "C" void kernel_launch(void* const* d_in, const int* in_sizes, int n_in,
                              void* d_out, int out_size, void* d_ws, size_t ws_size,
                              hipStream_t stream) {
  const float* x = (const float*)d_in[0];
  const float* enc = (const float*)d_in[1];
  const float* wq1 = (const float*)d_in[4];  const float* bq1 = (const float*)d_in[5];
  const float* wk1 = (const float*)d_in[6];  const float* bk1 = (const float*)d_in[7];
  const float* wv1 = (const float*)d_in[8];  const float* bv1 = (const float*)d_in[9];
  const float* wo1 = (const float*)d_in[10]; const float* bo1 = (const float*)d_in[11];
  const float* wq2 = (const float*)d_in[12]; const float* bq2 = (const float*)d_in[13];
  const float* wk2 = (const float*)d_in[14]; const float* bk2 = (const float*)d_in[15];
  const float* wv2 = (const float*)d_in[16]; const float* bv2 = (const float*)d_in[17];
  const float* wo2 = (const float*)d_in[18]; const float* bo2 = (const float*)d_in[19];
  const float* wff1 = (const float*)d_in[20]; const float* bff1 = (const float*)d_in[21];
  const float* wff2 = (const float*)d_in[22]; const float* bff2 = (const float*)d_in[23];
  const float* gamma1 = (const float*)d_in[24]; const float* beta1 = (const float*)d_in[25];
  const float* gamma2 = (const float*)d_in[26]; const float* beta2 = (const float*)d_in[27];
  const float* gamma3 = (const float*)d_in[28]; const float* beta3 = (const float*)d_in[29];

  float* out3 = (float*)d_out;
  float* sa_w = out3 + (long)8 * 1024 * 512;
  float* ca_w = sa_w + (long)64 * 1024 * 1024;

  char* w = (char*)d_ws;
  auto alloc = [&](long bytes) { char* p = w; w += (bytes + 255) & ~255L; return p; };
  bf16* xb     = (bf16*)alloc(8192L * 512 * 2);
  bf16* encb   = (bf16*)alloc(8192L * 512 * 2);
  bf16* wqkv1t = (bf16*)alloc(1536L * 512 * 2);
  bf16* wo1t   = (bf16*)alloc(512L * 512 * 2);
  bf16* wq2t   = (bf16*)alloc(512L * 512 * 2);
  bf16* wkv2t  = (bf16*)alloc(1024L * 512 * 2);
  bf16* wo2t   = (bf16*)alloc(512L * 512 * 2);
  bf16* wff1t  = (bf16*)alloc(2048L * 512 * 2);
  bf16* wff2t  = (bf16*)alloc(512L * 2048 * 2);
  float* bcat  = (float*)alloc(3072L * 4);  // bq1*S | bk1 | bv1 | bk2 | bv2 | bq2*S
  bf16* qkv    = (bf16*)alloc(8192L * 1536 * 2);
  bf16* q2b    = (bf16*)alloc(8192L * 512 * 2);
  bf16* kv2    = (bf16*)alloc(8192L * 1024 * 2);
  bf16* vt     = (bf16*)alloc(64L * 64 * 1024 * 2);
  bf16* vt2    = (bf16*)alloc(64L * 64 * 1024 * 2);
  bf16* ctx    = (bf16*)alloc(8192L * 512 * 2);
  bf16* out1b  = (bf16*)alloc(8192L * 512 * 2);
  bf16* out2b  = (bf16*)alloc(8192L * 512 * 2);
  bf16* ffh    = qkv;  // alias: qkv + q2b dead by FFN; spans 32MB

  // ---- prep (1 kernel) ----
  PrepPack pp;
  pp.x = x; pp.enc = enc; pp.xb = xb; pp.encb = encb;
  pp.d[0] = {wq1,  wqkv1t,               512,  512,  0,    QSCL};
  pp.d[1] = {wk1,  wqkv1t + 512L * 512,  512,  512,  256,  1.f};
  pp.d[2] = {wv1,  wqkv1t + 1024L * 512, 512,  512,  512,  1.f};
  pp.d[3] = {wo1,  wo1t,                 512,  512,  768,  1.f};
  pp.d[4] = {wq2,  wq2t,                 512,  512,  1024, QSCL};
  pp.d[5] = {wk2,  wkv2t,                512,  512,  1280, 1.f};
  pp.d[6] = {wv2,  wkv2t + 512L * 512,   512,  512,  1536, 1.f};
  pp.d[7] = {wo2,  wo2t,                 512,  512,  1792, 1.f};
  pp.d[8] = {wff1, wff1t,                512,  2048, 2048, 1.f};
  pp.d[9] = {wff2, wff2t,                2048, 512,  3072, 1.f};
  pp.bsrc[0] = bq1; pp.bsrc[1] = bk1; pp.bsrc[2] = bv1;
  pp.bsrc[3] = bk2; pp.bsrc[4] = bv2; pp.bsrc[5] = bq2;
  pp.bscl[0] = QSCL; pp.bscl[1] = 1.f; pp.bscl[2] = 1.f;
  pp.bscl[3] = 1.f;  pp.bscl[4] = 1.f; pp.bscl[5] = QSCL;
  pp.bdst = bcat;
  prep_k<<<12294, 256, 0, stream>>>(pp);

  // ================= self attention (+ overlapped cross K/V projection) ========
  gemm_qkv_k<<<768, 256, 0, stream>>>(xb, wqkv1t, qkv, bcat, vt);  // V -> vt fused
  attn_gemm_k<<<1024, 256, 0, stream>>>(
      qkv, 1536, qkv + 512, 1536, vt, sa_w, ctx,
      encb, 512, wkv2t, 512, kv2, 1024, bcat + 1536, 512, 8, vt2);  // V2 -> vt2 fused
  gemm_ln_k<float><<<256, 512, 0, stream>>>(
      ctx, 512, wo1t, bo1, x, gamma1, beta1, nullptr, out1b, 512);

  // ================= cross attention =================
  gemm_gl_k<2, 4, bf16, false><<<512, 256, 0, stream>>>(
      out1b, 512, wq2t, 512, q2b, 512, bcat + 2560, 512, 4);
  attn_k<false><<<512, 256, 0, stream>>>(
      q2b, 512, kv2, 1024, vt2, ca_w, ctx);
  gemm_ln_k<bf16><<<256, 512, 0, stream>>>(
      ctx, 512, wo2t, bo2, out1b, gamma2, beta2, nullptr, out2b, 512);

  // ================= FFN =================
  gemm_gl_k<4, 4, bf16, true><<<1024, 256, 0, stream>>>(
      out2b, 512, wff1t, 512, ffh, 2048, bff1, 512, 16);
  gemm_ln_k<bf16><<<256, 512, 0, stream>>>(
      ffh, 2048, wff2t, bff2, out2b, gamma3, beta3, out3, nullptr, 2048);
}

// Round 11
// 355.350 us; speedup vs baseline: 1.1111x; 1.0420x over previous
//
#include <hip/hip_runtime.h>
#include <hip/hip_bf16.h>

// DecoderLayer: B=8, T=S=1024, D=512, H=8, depth=64, F=2048. fp32 in/out.
// Outputs (concat in d_out): out3 [8,1024,512], sa_w [64,1024,1024], ca_w [64,1024,1024].
// Round 11: QKV + FFN1 ported to gemm8_k — 256^2 tile, BK=64, 8 waves, dbuf
// 128KB LDS with both-sides XOR swizzle (T2), raw s_barrier + counted vmcnt(8)
// (T4, never drained in-loop), 64 MFMA/barrier-pair, setprio (T5). Everything
// else identical to round 10. 9 nodes.

using bf16 = __hip_bfloat16;
typedef __attribute__((ext_vector_type(8))) short bf16x8v;
typedef __attribute__((ext_vector_type(4))) float f32x4;
typedef __attribute__((ext_vector_type(2))) float f32x2;
typedef __attribute__((ext_vector_type(2))) unsigned int u32x2;

#define DEVI __device__ __forceinline__

// 0.125 (1/sqrt(depth)) * log2(e): logits computed directly in exp2 units.
#define QSCL 0.18033688011112042f

DEVI short f2bs(float f) {
  bf16 h = __float2bfloat16(f);
  return *reinterpret_cast<short*>(&h);
}
DEVI bf16 f2b(float f) { return __float2bfloat16(f); }
DEVI float ex2(float x) { return __builtin_amdgcn_exp2f(x); }
DEVI float ldf(const float* p) { return *p; }
DEVI float ldf(const bf16* p) { return __bfloat162float(*p); }

DEVI void gload16(const bf16* g, bf16* l) {
  __builtin_amdgcn_global_load_lds(
      (const __attribute__((address_space(1))) void*)g,
      (__attribute__((address_space(3))) void*)l, 16, 0, 0);
}

// wave-uniform counted vmcnt wait (immediates only)
DEVI void vmwait(int n) {
  if (n == 0)       asm volatile("s_waitcnt vmcnt(0)" ::: "memory");
  else if (n == 1)  asm volatile("s_waitcnt vmcnt(1)" ::: "memory");
  else if (n == 2)  asm volatile("s_waitcnt vmcnt(2)" ::: "memory");
  else if (n == 4)  asm volatile("s_waitcnt vmcnt(4)" ::: "memory");
  else if (n == 6)  asm volatile("s_waitcnt vmcnt(6)" ::: "memory");
  else if (n == 8)  asm volatile("s_waitcnt vmcnt(8)" ::: "memory");
  else              asm volatile("s_waitcnt vmcnt(10)" ::: "memory");
}
#define SBAR() __builtin_amdgcn_sched_barrier(0)

// ---------------- fused prep: casts + weight transposes + bias concat ----------
struct WDesc { const float* src; bf16* dst; int K; int N; int toff; float scl; };
struct PrepPack {
  const float* x; const float* enc; bf16* xb; bf16* encb;
  WDesc d[10];
  const float* bsrc[6]; float bscl[6]; float* bdst;
};

__global__ __launch_bounds__(256) void prep_k(PrepPack p) {
  const int bid = blockIdx.x;
  if (bid < 8192) {
    const float* s = (bid < 4096) ? p.x : p.enc;
    bf16* d = (bid < 4096) ? p.xb : p.encb;
    long i = ((long)(bid & 4095) * 256 + threadIdx.x) * 4;
    f32x4 v = *reinterpret_cast<const f32x4*>(s + i);
    union { short sh[4]; long l; } u;
    u.sh[0] = f2bs(v[0]); u.sh[1] = f2bs(v[1]); u.sh[2] = f2bs(v[2]); u.sh[3] = f2bs(v[3]);
    *reinterpret_cast<long*>(d + i) = u.l;
    return;
  }
  if (bid < 12288) {
    const int t = bid - 8192;
    int wi = 0;
#pragma unroll
    for (int i = 1; i < 10; i++)
      if (t >= p.d[i].toff) wi = i;
    const WDesc d = p.d[wi];
    const int lt = t - d.toff;
    const int nx = d.N >> 5;
    const int n0 = (lt % nx) * 32, k0 = (lt / nx) * 32;
    __shared__ float tile[32][33];
    const int tx = threadIdx.x & 31, ty = threadIdx.x >> 5;
#pragma unroll
    for (int i = 0; i < 32; i += 8)
      tile[ty + i][tx] = d.src[(long)(k0 + ty + i) * d.N + n0 + tx] * d.scl;
    __syncthreads();
#pragma unroll
    for (int i = 0; i < 32; i += 8)
      d.dst[(long)(n0 + ty + i) * d.K + k0 + tx] = f2b(tile[tx][ty + i]);
    return;
  }
  const int i = bid - 12288;
  const int e = threadIdx.x * 2;
  f32x2 v = *reinterpret_cast<const f32x2*>(p.bsrc[i] + e);
  v[0] *= p.bscl[i]; v[1] *= p.bscl[i];
  *reinterpret_cast<f32x2*>(p.bdst + i * 512 + e) = v;
}

// ---------------- GEMM body (128^2, shared) ------------
template <int FM, int FN, typename TC, bool RELU, bool VTOUT>
DEVI void gemm_body(int bid, int nblocks,
                    const bf16* __restrict__ A, int lda,
                    const bf16* __restrict__ Bt, int ldb,
                    TC* __restrict__ C, int ldc,
                    const float* __restrict__ bias, int K, int tiles_n,
                    bf16* sA, bf16* sB,
                    bf16* __restrict__ vtout, int vcol0) {
  constexpr int BM = 32 * FM, BN = 32 * FN;
  const int tm8 = (nblocks / tiles_n) >> 3;
  const int r8 = bid >> 3;
  const int tm = (bid & 7) + ((r8 % tm8) << 3);
  const int tn = r8 / tm8;
  const int tid = threadIdx.x, wave = tid >> 6, lane = tid & 63;
  const int wr = wave >> 1, wc = wave & 1;
  const int l16 = lane & 15, lhi = lane >> 4;
  const int srow = lane >> 2, scol = (lane & 3) * 8;

  const bf16* Ab = A + (long)(tm * BM + wave * (BM / 4) + srow) * lda + scol;
  const bf16* Bb = Bt + (long)(tn * BN + wave * (BN / 4) + srow) * ldb + scol;

  auto stage = [&](int buf, int k0) {
#pragma unroll
    for (int i = 0; i < BM / 64; i++)
      gload16(Ab + (long)(i * 16) * lda + k0, sA + buf * BM * 32 + (wave * (BM / 4) + i * 16) * 32);
#pragma unroll
    for (int i = 0; i < BN / 64; i++)
      gload16(Bb + (long)(i * 16) * ldb + k0, sB + buf * BN * 32 + (wave * (BN / 4) + i * 16) * 32);
  };

  stage(0, 0);
  __syncthreads();

  f32x4 acc[FM][FN] = {};
  int cur = 0;
  for (int k0 = 0; k0 < K; k0 += 32) {
    if (k0 + 32 < K) stage(cur ^ 1, k0 + 32);
    bf16x8v af[FM], bfr[FN];
#pragma unroll
    for (int m = 0; m < FM; m++)
      af[m] = *reinterpret_cast<const bf16x8v*>(
          sA + cur * BM * 32 + (wr * 16 * FM + m * 16 + l16) * 32 + lhi * 8);
#pragma unroll
    for (int n = 0; n < FN; n++)
      bfr[n] = *reinterpret_cast<const bf16x8v*>(
          sB + cur * BN * 32 + (wc * 16 * FN + n * 16 + l16) * 32 + lhi * 8);
#pragma unroll
    for (int m = 0; m < FM; m++)
#pragma unroll
      for (int n = 0; n < FN; n++)
        acc[m][n] = __builtin_amdgcn_mfma_f32_16x16x32_bf16(af[m], bfr[n], acc[m][n], 0, 0, 0);
    if (k0 + 32 < K) {
      __syncthreads();
      cur ^= 1;
    }
  }

#pragma unroll
  for (int m = 0; m < FM; m++) {
    const int gr0 = tm * BM + wr * 16 * FM + m * 16 + lhi * 4;
#pragma unroll
    for (int n = 0; n < FN; n++) {
      const int gc = tn * BN + wc * 16 * FN + n * 16 + l16;
      const float bv = bias ? bias[gc] : 0.f;
      if (VTOUT && gc >= vcol0) {
        const int vc = gc - vcol0;
        bf16* vdst = vtout + ((long)(((gr0 >> 10) << 3) + (vc >> 6)) << 16)
                           + ((long)(vc & 63) << 10) + (gr0 & 1023);
        union { short sh[4]; u32x2 u2; } pk;
#pragma unroll
        for (int j = 0; j < 4; j++) pk.sh[j] = f2bs(acc[m][n][j] + bv);
        *reinterpret_cast<u32x2*>(vdst) = pk.u2;
      } else {
#pragma unroll
        for (int j = 0; j < 4; j++) {
          float v = acc[m][n][j] + bv;
          if (RELU) v = fmaxf(v, 0.f);
          if constexpr (sizeof(TC) == 4)
            C[(long)(gr0 + j) * ldc + gc] = v;
          else
            C[(long)(gr0 + j) * ldc + gc] = f2b(v);
        }
      }
    }
  }
}

template <int FM, int FN, typename TC, bool RELU>
__global__ __launch_bounds__(256) void gemm_gl_k(
    const bf16* __restrict__ A, int lda, const bf16* __restrict__ Bt, int ldb,
    TC* __restrict__ C, int ldc, const float* __restrict__ bias, int K, int tiles_n) {
  __shared__ bf16 sA[2 * 32 * FM * 32];
  __shared__ bf16 sB[2 * 32 * FN * 32];
  gemm_body<FM, FN, TC, RELU, false>(blockIdx.x, gridDim.x, A, lda, Bt, ldb, C, ldc,
                                     bias, K, tiles_n, sA, sB, nullptr, 0);
}

// ---------------- gemm8_k: 256^2 tile, BK=64, 8 waves, swizzled LDS, counted vmcnt
// LDS: sA[2][256*64] + sB[2][256*64] bf16 = 128 KB. 1 block/CU, 2 waves/SIMD.
// Schedule per K-tile: vmwait(8) -> s_barrier -> {4 sub-phase MFMA clusters,
// 64 MFMA total} -> s_barrier -> stage(kt+2). Loads never drained in-loop.
template <bool RELU, bool VTOUT>
__global__ __launch_bounds__(512, 2) void gemm8_k(
    const bf16* __restrict__ A, int lda, const bf16* __restrict__ Bt, int ldb,
    bf16* __restrict__ C, int ldc, const float* __restrict__ bias, int K, int tiles_n,
    bf16* __restrict__ vtout, int vcol0) {
  __shared__ bf16 sA[2][256 * 64];
  __shared__ bf16 sB[2][256 * 64];
  const int NKT = K >> 6;
  const int bid = blockIdx.x;
  const int tm8 = ((int)gridDim.x / tiles_n) >> 3;
  const int r8 = bid >> 3;
  const int tm = (bid & 7) + ((r8 % tm8) << 3);
  const int tn = r8 / tm8;
  const int tid = threadIdx.x, wave = tid >> 6, lane = tid & 63;
  const int wm = wave >> 2, wn = wave & 3;
  const int l16 = lane & 15, lhi = lane >> 4;

  // staging: per pass, 512 threads cover 64 rows x 128B; 4 passes per tensor.
  // source col pre-swizzled (inverse of the read XOR; both are the same involution)
  const int srow = tid >> 3;
  const int scol = ((tid & 7) ^ (srow & 7)) * 8;  // elems
  const bf16* Ag = A + (long)(tm * 256 + srow) * lda + scol;
  const bf16* Bg = Bt + (long)(tn * 256 + srow) * ldb + scol;

  auto stage = [&](int buf, int kt) {
    const int kofs = kt * 64;
#pragma unroll
    for (int p = 0; p < 4; p++)
      gload16(Ag + (long)(p * 64) * lda + kofs, &sA[buf][(p * 64 + wave * 8) * 64]);
#pragma unroll
    for (int p = 0; p < 4; p++)
      gload16(Bg + (long)(p * 64) * ldb + kofs, &sB[buf][(p * 64 + wave * 8) * 64]);
  };

  stage(0, 0);
  if (NKT > 1) stage(1, 1);

  f32x4 acc[8][4] = {};
  const int sxor = (l16 & 7) << 4;                  // read-side XOR (bytes)
  const int aoff0 = ((lhi * 16) ^ sxor) >> 1;       // ks=0, elems
  const int aoff1 = ((64 + lhi * 16) ^ sxor) >> 1;  // ks=1, elems

#pragma unroll 1
  for (int kt = 0; kt < NKT; kt++) {
    const int buf = kt & 1;
    vmwait((kt + 1 < NKT) ? 8 : 0);  // own shares of K-tile kt landed
    SBAR();
    __builtin_amdgcn_s_barrier();    // collective: buf fully resident
    SBAR();
#pragma unroll
    for (int ks = 0; ks < 2; ks++) {
      const int ao = ks ? aoff1 : aoff0;
      bf16x8v bfr[4];
#pragma unroll
      for (int n = 0; n < 4; n++)
        bfr[n] = *reinterpret_cast<const bf16x8v*>(
            &sB[buf][(wn * 64 + n * 16 + l16) * 64 + ao]);
#pragma unroll
      for (int mh = 0; mh < 2; mh++) {
        bf16x8v af[4];
#pragma unroll
        for (int mm = 0; mm < 4; mm++)
          af[mm] = *reinterpret_cast<const bf16x8v*>(
              &sA[buf][(wm * 128 + (mh * 4 + mm) * 16 + l16) * 64 + ao]);
        __builtin_amdgcn_s_setprio(1);
#pragma unroll
        for (int mm = 0; mm < 4; mm++)
#pragma unroll
          for (int n = 0; n < 4; n++)
            acc[mh * 4 + mm][n] = __builtin_amdgcn_mfma_f32_16x16x32_bf16(
                af[mm], bfr[n], acc[mh * 4 + mm][n], 0, 0, 0);
        __builtin_amdgcn_s_setprio(0);
      }
    }
    SBAR();
    __builtin_amdgcn_s_barrier();    // all waves done reading buf -> WAR-safe
    SBAR();
    if (kt + 2 < NKT) stage(buf, kt + 2);
  }

#pragma unroll
  for (int m = 0; m < 8; m++) {
    const int gr0 = tm * 256 + wm * 128 + m * 16 + lhi * 4;
#pragma unroll
    for (int n = 0; n < 4; n++) {
      const int gc = tn * 256 + wn * 64 + n * 16 + l16;
      const float bv = bias[gc];
      if (VTOUT && gc >= vcol0) {
        const int vc = gc - vcol0;
        bf16* vdst = vtout + ((long)(((gr0 >> 10) << 3) + (vc >> 6)) << 16)
                           + ((long)(vc & 63) << 10) + (gr0 & 1023);
        union { short sh[4]; u32x2 u2; } pk;
#pragma unroll
        for (int j = 0; j < 4; j++) pk.sh[j] = f2bs(acc[m][n][j] + bv);
        *reinterpret_cast<u32x2*>(vdst) = pk.u2;
      } else {
#pragma unroll
        for (int j = 0; j < 4; j++) {
          float v = acc[m][n][j] + bv;
          if (RELU) v = fmaxf(v, 0.f);
          C[(long)(gr0 + j) * ldc + gc] = f2b(v);
        }
      }
    }
  }
}

// ---------------- attention body: counted-vmcnt pipelined 2-pass flash ----------
// (round-8 verified version) LDS 34816 B: Kst[3][2048] | Vst[3][2048] | pst[4][1280]
template <bool CAUSAL>
DEVI void attn_body(int bid, char* smem,
                    const bf16* __restrict__ Qm, int ldq,
                    const bf16* __restrict__ Km, int ldk,
                    const bf16* __restrict__ vt,
                    float* __restrict__ P, bf16* __restrict__ ctx) {
  bf16* Kst = (bf16*)smem;      // 3 x 2048 elems
  bf16* Vst = Kst + 3 * 2048;   // 3 x 2048
  bf16* pst = Vst + 3 * 2048;   // 4 x 1280
  const int bh = bid & 63;
  const int g = bid >> 6;
  const int qx = CAUSAL ? ((g < 4) ? g : 11 - g) : g;  // anti-correlated pairs
  const int b = bh >> 3, h = bh & 7;
  const int tid = threadIdx.x, wave = tid >> 6, lane = tid & 63;
  const int l16 = lane & 15, lhi = lane >> 4;
  const int q0 = qx * 128 + wave * 32;
  const bf16* Qb = Qm + (long)(b * 1024 + q0) * ldq + h * 64;
  const bf16* Kb = Km + (long)b * 1024 * ldk + h * 64;
  const bf16* Vb = vt + (long)bh * 64 * 1024;

  const int nun = CAUSAL ? (q0 >> 5) : 32;
  const int nchw = CAUSAL ? nun + 1 : 32;
  const int nchb = CAUSAL ? qx * 4 + 4 : 32;

  const bf16* ksrc = Kb + (long)(tid >> 3) * ldk + ((tid & 7) ^ ((tid >> 3) & 7)) * 8;
  const bf16* vsrc = Vb + (long)(tid >> 2) * 1024 + ((tid & 3) ^ ((tid >> 2) & 3)) * 8;

  int kfo[2][2];
#pragma unroll
  for (int cc = 0; cc < 2; cc++) {
    const int r = cc * 16 + l16;
#pragma unroll
    for (int ks = 0; ks < 2; ks++)
      kfo[cc][ks] = r * 64 + (((ks * 64 + lhi * 16) ^ ((r & 7) << 4)) >> 1);
  }
  int vfo[4];
#pragma unroll
  for (int n = 0; n < 4; n++) {
    const int r = n * 16 + l16;
    vfo[n] = r * 32 + (((lhi * 16) ^ ((r & 3) << 4)) >> 1);
  }

  bf16x8v qB[2][2];
#pragma unroll
  for (int m = 0; m < 2; m++)
#pragma unroll
    for (int ks = 0; ks < 2; ks++)
      qB[m][ks] = *reinterpret_cast<const bf16x8v*>(
          Qb + (long)(m * 16 + l16) * ldq + ks * 32 + lhi * 8);

  float ll[2] = {0.f, 0.f};

  // ================ pass 1: l-sum only (no max), K triple-buffered ================
  gload16(ksrc, Kst + wave * 512);
  gload16(ksrc + (long)32 * ldk, Kst + 2048 + wave * 512);
#pragma unroll 1
  for (int ch = 0; ch < nchb; ch++) {
    if (ch + 1 < nchb) vmwait(1); else vmwait(0);
    SBAR();
    __builtin_amdgcn_s_barrier();
    SBAR();
    if (ch + 2 < nchb)
      gload16(ksrc + (long)(ch + 2) * 32 * ldk, Kst + ((ch + 2) % 3) * 2048 + wave * 512);
    if (ch < nchw) {
      const int bo = (ch % 3) * 2048;
      bf16x8v kf[2][2];
#pragma unroll
      for (int cc = 0; cc < 2; cc++)
#pragma unroll
        for (int ks = 0; ks < 2; ks++)
          kf[cc][ks] = *reinterpret_cast<const bf16x8v*>(&Kst[bo + kfo[cc][ks]]);
      const bool diag = CAUSAL && (ch == nun);
#pragma unroll
      for (int m = 0; m < 2; m++) {
        f32x4 s0 = {}, s1 = {};
        s0 = __builtin_amdgcn_mfma_f32_16x16x32_bf16(kf[0][0], qB[m][0], s0, 0, 0, 0);
        s0 = __builtin_amdgcn_mfma_f32_16x16x32_bf16(kf[0][1], qB[m][1], s0, 0, 0, 0);
        s1 = __builtin_amdgcn_mfma_f32_16x16x32_bf16(kf[1][0], qB[m][0], s1, 0, 0, 0);
        s1 = __builtin_amdgcn_mfma_f32_16x16x32_bf16(kf[1][1], qB[m][1], s1, 0, 0, 0);
        if (diag) {
          const int rq = m * 16 + l16;
#pragma unroll
          for (int j = 0; j < 4; j++) {
            s0[j] = (lhi * 4 + j <= rq) ? s0[j] : -1e30f;   // exp2 -> 0 exactly
            s1[j] = (16 + lhi * 4 + j <= rq) ? s1[j] : -1e30f;
          }
        }
        float sum = 0.f;
#pragma unroll
        for (int j = 0; j < 4; j++) sum += ex2(s0[j]) + ex2(s1[j]);
        ll[m] += sum;
      }
    }
  }
  __syncthreads();  // pass boundary

  float il[2];
#pragma unroll
  for (int m = 0; m < 2; m++) {
    float lo = ll[m];
    lo += __shfl_xor(lo, 16);
    lo += __shfl_xor(lo, 32);
    il[m] = 1.f / lo;
  }

  // ================ pass 2: P write + PV, K+V triple-buffered ================
  f32x4 pv[2][4] = {};
  float* Pg = P + (long)bh * 1024 * 1024 + (long)q0 * 1024;
  gload16(ksrc, Kst + wave * 512);
  gload16(vsrc, Vst + wave * 512);
  gload16(ksrc + (long)32 * ldk, Kst + 2048 + wave * 512);
  gload16(vsrc + 32, Vst + 2048 + wave * 512);
#pragma unroll 1
  for (int ch = 0; ch < nchb; ch++) {
    const int Sa = (ch >= 2 && ch - 2 < nchw) ? 4 : 0;
    const int Lr = (ch + 1 < nchb) ? 2 : 0;
    const int Sb = (ch >= 1 && ch - 1 < nchw) ? 4 : 0;
    vmwait(Sa + Lr + Sb);
    SBAR();
    __builtin_amdgcn_s_barrier();
    SBAR();
    if (ch + 2 < nchb) {
      gload16(ksrc + (long)(ch + 2) * 32 * ldk, Kst + ((ch + 2) % 3) * 2048 + wave * 512);
      gload16(vsrc + (ch + 2) * 32, Vst + ((ch + 2) % 3) * 2048 + wave * 512);
    }
    if (ch < nchw) {
      const int kc = ch * 32;
      const int bo = (ch % 3) * 2048;
      bf16x8v kf[2][2], vf[4];
#pragma unroll
      for (int cc = 0; cc < 2; cc++)
#pragma unroll
        for (int ks = 0; ks < 2; ks++)
          kf[cc][ks] = *reinterpret_cast<const bf16x8v*>(&Kst[bo + kfo[cc][ks]]);
#pragma unroll
      for (int n = 0; n < 4; n++)
        vf[n] = *reinterpret_cast<const bf16x8v*>(&Vst[bo + vfo[n]]);
      const bool diag = CAUSAL && (ch == nun);
#pragma unroll
      for (int m = 0; m < 2; m++) {
        f32x4 s0 = {}, s1 = {};
        s0 = __builtin_amdgcn_mfma_f32_16x16x32_bf16(kf[0][0], qB[m][0], s0, 0, 0, 0);
        s0 = __builtin_amdgcn_mfma_f32_16x16x32_bf16(kf[0][1], qB[m][1], s0, 0, 0, 0);
        s1 = __builtin_amdgcn_mfma_f32_16x16x32_bf16(kf[1][0], qB[m][0], s1, 0, 0, 0);
        s1 = __builtin_amdgcn_mfma_f32_16x16x32_bf16(kf[1][1], qB[m][1], s1, 0, 0, 0);
        if (diag) {
          const int rq = m * 16 + l16;
#pragma unroll
          for (int j = 0; j < 4; j++) {
            s0[j] = (lhi * 4 + j <= rq) ? s0[j] : -1e30f;
            s1[j] = (16 + lhi * 4 + j <= rq) ? s1[j] : -1e30f;
          }
        }
        f32x4 p0, p1;
#pragma unroll
        for (int j = 0; j < 4; j++) {
          p0[j] = ex2(s0[j]) * il[m];
          p1[j] = ex2(s1[j]) * il[m];
        }
        const int prow = (m * 16 + l16) * 40;
        union { short s[4]; u32x2 u; } pk0, pk1;
#pragma unroll
        for (int j = 0; j < 4; j++) { pk0.s[j] = f2bs(p0[j]); pk1.s[j] = f2bs(p1[j]); }
        *reinterpret_cast<u32x2*>(&pst[wave * 1280 + prow + lhi * 4]) = pk0.u;
        *reinterpret_cast<u32x2*>(&pst[wave * 1280 + prow + 16 + lhi * 4]) = pk1.u;
      }
#pragma unroll
      for (int m = 0; m < 2; m++) {
        bf16x8v pa = *reinterpret_cast<const bf16x8v*>(
            &pst[wave * 1280 + (m * 16 + l16) * 40 + lhi * 8]);
#pragma unroll
        for (int n = 0; n < 4; n++)
          pv[m][n] = __builtin_amdgcn_mfma_f32_16x16x32_bf16(pa, vf[n], pv[m][n], 0, 0, 0);
      }
      // flush P from pst (bf16 -> f32 bitshift): 4 nt-stores, 8 rows x 128B each
#pragma unroll
      for (int f = 0; f < 4; f++) {
        const int row = f * 8 + (lane >> 3);
        u32x2 raw = *reinterpret_cast<const u32x2*>(
            &pst[wave * 1280 + row * 40 + (lane & 7) * 4]);
        union { unsigned int u; float fl; } c0, c1, c2, c3;
        c0.u = raw[0] << 16; c1.u = raw[0] & 0xffff0000u;
        c2.u = raw[1] << 16; c3.u = raw[1] & 0xffff0000u;
        f32x4 val = {c0.fl, c1.fl, c2.fl, c3.fl};
        __builtin_nontemporal_store(
            val, reinterpret_cast<f32x4*>(Pg + (long)row * 1024 + kc + (lane & 7) * 4));
      }
    }
  }

  bf16* cb = ctx + (long)(b * 1024 + q0) * 512 + h * 64;
#pragma unroll
  for (int m = 0; m < 2; m++)
#pragma unroll
    for (int n = 0; n < 4; n++)
#pragma unroll
      for (int j = 0; j < 4; j++)
        cb[(long)(m * 16 + lhi * 4 + j) * 512 + n * 16 + l16] = f2b(pv[m][n][j]);
}

template <bool CAUSAL>
__global__ __launch_bounds__(256) void attn_k(
    const bf16* __restrict__ Qm, int ldq, const bf16* __restrict__ Km, int ldk,
    const bf16* __restrict__ vt, float* __restrict__ P, bf16* __restrict__ ctx) {
  __shared__ __align__(16) char smem[34816];
  attn_body<CAUSAL>(blockIdx.x, smem, Qm, ldq, Km, ldk, vt, P, ctx);
}

// merged: blocks 0..511 self-attention, 512..1023 kv2 GEMM (+fused vt2 output)
__global__ __launch_bounds__(256) void attn_gemm_k(
    const bf16* __restrict__ Qm, int ldq, const bf16* __restrict__ Km, int ldk,
    const bf16* __restrict__ vt, float* __restrict__ P, bf16* __restrict__ ctx,
    const bf16* __restrict__ A, int lda, const bf16* __restrict__ Bt, int ldb,
    bf16* __restrict__ C, int ldc, const float* __restrict__ bias, int K, int tiles_n,
    bf16* __restrict__ vt2) {
  __shared__ __align__(16) char smem[34816];
  if (blockIdx.x < 512) {
    attn_body<true>(blockIdx.x, smem, Qm, ldq, Km, ldk, vt, P, ctx);
  } else {
    bf16* sA = (bf16*)smem;
    gemm_body<4, 4, bf16, false, true>(blockIdx.x - 512, 512, A, lda, Bt, ldb,
                                       C, ldc, bias, K, tiles_n, sA, sA + 8192,
                                       vt2, 512);
  }
}

// ---------------- GEMM + residual add + LayerNorm fused epilogue ----------------
template <typename TR>
__global__ __launch_bounds__(512) void gemm_ln_k(
    const bf16* __restrict__ A, int lda, const bf16* __restrict__ Bt,
    const float* __restrict__ bias, const TR* __restrict__ resid,
    const float* __restrict__ gamma, const float* __restrict__ beta,
    float* __restrict__ outf, bf16* __restrict__ outb, int K) {
  __shared__ bf16 sA[2][32 * 32];
  __shared__ bf16 sB[2][512 * 32];
  __shared__ float red[2][32][8];
  __shared__ f32x2 mr[32];
  const int tm = blockIdx.x;
  const int tid = threadIdx.x, wave = tid >> 6, lane = tid & 63;
  const int l16 = lane & 15, lhi = lane >> 4;

  const bf16* Asrc = A + (long)(tm * 32 + (tid >> 2)) * lda + (tid & 3) * 8;
  const bf16* Bsrc = Bt + (long)(tid >> 2) * K + (tid & 3) * 8;

  auto stage = [&](int buf, int k0) {
    if (tid < 128) gload16(Asrc + k0, &sA[buf][(tid >> 6) * 512]);
#pragma unroll
    for (int p = 0; p < 4; p++)
      gload16(Bsrc + (long)(p * 128) * K + k0, &sB[buf][p * 4096 + wave * 512]);
  };

  stage(0, 0);
  __syncthreads();

  f32x4 acc[2][4] = {};
  int cur = 0;
  for (int k0 = 0; k0 < K; k0 += 32) {
    if (k0 + 32 < K) stage(cur ^ 1, k0 + 32);
    bf16x8v af[2], bfr[4];
#pragma unroll
    for (int m = 0; m < 2; m++)
      af[m] = *reinterpret_cast<const bf16x8v*>(&sA[cur][(m * 16 + l16) * 32 + lhi * 8]);
#pragma unroll
    for (int n = 0; n < 4; n++)
      bfr[n] = *reinterpret_cast<const bf16x8v*>(&sB[cur][(wave * 64 + n * 16 + l16) * 32 + lhi * 8]);
#pragma unroll
    for (int m = 0; m < 2; m++)
#pragma unroll
      for (int n = 0; n < 4; n++)
        acc[m][n] = __builtin_amdgcn_mfma_f32_16x16x32_bf16(af[m], bfr[n], acc[m][n], 0, 0, 0);
    if (k0 + 32 < K) {
      __syncthreads();
      cur ^= 1;
    }
  }

  float bv[4], gm[4], bt[4];
#pragma unroll
  for (int n = 0; n < 4; n++) {
    const int gc = wave * 64 + n * 16 + l16;
    bv[n] = bias[gc]; gm[n] = gamma[gc]; bt[n] = beta[gc];
  }
  float v[2][4][4], rs[2][4], rq[2][4];
#pragma unroll
  for (int m = 0; m < 2; m++)
#pragma unroll
    for (int j = 0; j < 4; j++) { rs[m][j] = 0.f; rq[m][j] = 0.f; }
#pragma unroll
  for (int m = 0; m < 2; m++) {
#pragma unroll
    for (int j = 0; j < 4; j++) {
      const long grow = tm * 32 + m * 16 + lhi * 4 + j;
#pragma unroll
      for (int n = 0; n < 4; n++) {
        const int gc = wave * 64 + n * 16 + l16;
        const float val = acc[m][n][j] + bv[n] + ldf(resid + grow * 512 + gc);
        v[m][n][j] = val;
        rs[m][j] += val;
        rq[m][j] += val * val;
      }
    }
  }
#pragma unroll
  for (int m = 0; m < 2; m++)
#pragma unroll
    for (int j = 0; j < 4; j++)
#pragma unroll
      for (int off = 1; off <= 8; off <<= 1) {
        rs[m][j] += __shfl_xor(rs[m][j], off);
        rq[m][j] += __shfl_xor(rq[m][j], off);
      }
  if (l16 == 0) {
#pragma unroll
    for (int m = 0; m < 2; m++)
#pragma unroll
      for (int j = 0; j < 4; j++) {
        red[0][m * 16 + lhi * 4 + j][wave] = rs[m][j];
        red[1][m * 16 + lhi * 4 + j][wave] = rq[m][j];
      }
  }
  __syncthreads();
  if (tid < 32) {
    float s = 0.f, q = 0.f;
#pragma unroll
    for (int w = 0; w < 8; w++) { s += red[0][tid][w]; q += red[1][tid][w]; }
    const float mean = s * (1.f / 512.f);
    const float var = q * (1.f / 512.f) - mean * mean;
    f32x2 o = {mean, rsqrtf(var + 1e-5f)};
    mr[tid] = o;
  }
  __syncthreads();
#pragma unroll
  for (int m = 0; m < 2; m++) {
#pragma unroll
    for (int j = 0; j < 4; j++) {
      const int row = m * 16 + lhi * 4 + j;
      const f32x2 mrv = mr[row];
      const long grow = tm * 32 + row;
#pragma unroll
      for (int n = 0; n < 4; n++) {
        const int gc = wave * 64 + n * 16 + l16;
        const float o = (v[m][n][j] - mrv[0]) * mrv[1] * gm[n] + bt[n];
        if (outf) outf[grow * 512 + gc] = o;
        if (outb) outb[grow * 512 + gc] = f2b(o);
      }
    }
  }
}

extern "C" void kernel_launch(void* const* d_in, const int* in_sizes, int n_in,
                              void* d_out, int out_size, void* d_ws, size_t ws_size,
                              hipStream_t stream) {
  const float* x = (const float*)d_in[0];
  const float* enc = (const float*)d_in[1];
  const float* wq1 = (const float*)d_in[4];  const float* bq1 = (const float*)d_in[5];
  const float* wk1 = (const float*)d_in[6];  const float* bk1 = (const float*)d_in[7];
  const float* wv1 = (const float*)d_in[8];  const float* bv1 = (const float*)d_in[9];
  const float* wo1 = (const float*)d_in[10]; const float* bo1 = (const float*)d_in[11];
  const float* wq2 = (const float*)d_in[12]; const float* bq2 = (const float*)d_in[13];
  const float* wk2 = (const float*)d_in[14]; const float* bk2 = (const float*)d_in[15];
  const float* wv2 = (const float*)d_in[16]; const float* bv2 = (const float*)d_in[17];
  const float* wo2 = (const float*)d_in[18]; const float* bo2 = (const float*)d_in[19];
  const float* wff1 = (const float*)d_in[20]; const float* bff1 = (const float*)d_in[21];
  const float* wff2 = (const float*)d_in[22]; const float* bff2 = (const float*)d_in[23];
  const float* gamma1 = (const float*)d_in[24]; const float* beta1 = (const float*)d_in[25];
  const float* gamma2 = (const float*)d_in[26]; const float* beta2 = (const float*)d_in[27];
  const float* gamma3 = (const float*)d_in[28]; const float* beta3 = (const float*)d_in[29];

  float* out3 = (float*)d_out;
  float* sa_w = out3 + (long)8 * 1024 * 512;
  float* ca_w = sa_w + (long)64 * 1024 * 1024;

  char* w = (char*)d_ws;
  auto alloc = [&](long bytes) { char* p = w; w += (bytes + 255) & ~255L; return p; };
  bf16* xb     = (bf16*)alloc(8192L * 512 * 2);
  bf16* encb   = (bf16*)alloc(8192L * 512 * 2);
  bf16* wqkv1t = (bf16*)alloc(1536L * 512 * 2);
  bf16* wo1t   = (bf16*)alloc(512L * 512 * 2);
  bf16* wq2t   = (bf16*)alloc(512L * 512 * 2);
  bf16* wkv2t  = (bf16*)alloc(1024L * 512 * 2);
  bf16* wo2t   = (bf16*)alloc(512L * 512 * 2);
  bf16* wff1t  = (bf16*)alloc(2048L * 512 * 2);
  bf16* wff2t  = (bf16*)alloc(512L * 2048 * 2);
  float* bcat  = (float*)alloc(3072L * 4);  // bq1*S | bk1 | bv1 | bk2 | bv2 | bq2*S
  bf16* qkv    = (bf16*)alloc(8192L * 1536 * 2);
  bf16* q2b    = (bf16*)alloc(8192L * 512 * 2);
  bf16* kv2    = (bf16*)alloc(8192L * 1024 * 2);
  bf16* vt     = (bf16*)alloc(64L * 64 * 1024 * 2);
  bf16* vt2    = (bf16*)alloc(64L * 64 * 1024 * 2);
  bf16* ctx    = (bf16*)alloc(8192L * 512 * 2);
  bf16* out1b  = (bf16*)alloc(8192L * 512 * 2);
  bf16* out2b  = (bf16*)alloc(8192L * 512 * 2);
  bf16* ffh    = qkv;  // alias: qkv + q2b dead by FFN; spans 32MB

  // ---- prep (1 kernel) ----
  PrepPack pp;
  pp.x = x; pp.enc = enc; pp.xb = xb; pp.encb = encb;
  pp.d[0] = {wq1,  wqkv1t,               512,  512,  0,    QSCL};
  pp.d[1] = {wk1,  wqkv1t + 512L * 512,  512,  512,  256,  1.f};
  pp.d[2] = {wv1,  wqkv1t + 1024L * 512, 512,  512,  512,  1.f};
  pp.d[3] = {wo1,  wo1t,                 512,  512,  768,  1.f};
  pp.d[4] = {wq2,  wq2t,                 512,  512,  1024, QSCL};
  pp.d[5] = {wk2,  wkv2t,                512,  512,  1280, 1.f};
  pp.d[6] = {wv2,  wkv2t + 512L * 512,   512,  512,  1536, 1.f};
  pp.d[7] = {wo2,  wo2t,                 512,  512,  1792, 1.f};
  pp.d[8] = {wff1, wff1t,                512,  2048, 2048, 1.f};
  pp.d[9] = {wff2, wff2t,                2048, 512,  3072, 1.f};
  pp.bsrc[0] = bq1; pp.bsrc[1] = bk1; pp.bsrc[2] = bv1;
  pp.bsrc[3] = bk2; pp.bsrc[4] = bv2; pp.bsrc[5] = bq2;
  pp.bscl[0] = QSCL; pp.bscl[1] = 1.f; pp.bscl[2] = 1.f;
  pp.bscl[3] = 1.f;  pp.bscl[4] = 1.f; pp.bscl[5] = QSCL;
  pp.bdst = bcat;
  prep_k<<<12294, 256, 0, stream>>>(pp);

  // ================= self attention (+ overlapped cross K/V projection) ========
  gemm8_k<false, true><<<192, 512, 0, stream>>>(
      xb, 512, wqkv1t, 512, qkv, 1536, bcat, 512, 6, vt, 1024);  // V -> vt fused
  attn_gemm_k<<<1024, 256, 0, stream>>>(
      qkv, 1536, qkv + 512, 1536, vt, sa_w, ctx,
      encb, 512, wkv2t, 512, kv2, 1024, bcat + 1536, 512, 8, vt2);  // V2 -> vt2 fused
  gemm_ln_k<float><<<256, 512, 0, stream>>>(
      ctx, 512, wo1t, bo1, x, gamma1, beta1, nullptr, out1b, 512);

  // ================= cross attention =================
  gemm_gl_k<2, 4, bf16, false><<<512, 256, 0, stream>>>(
      out1b, 512, wq2t, 512, q2b, 512, bcat + 2560, 512, 4);
  attn_k<false><<<512, 256, 0, stream>>>(
      q2b, 512, kv2, 1024, vt2, ca_w, ctx);
  gemm_ln_k<bf16><<<256, 512, 0, stream>>>(
      ctx, 512, wo2t, bo2, out1b, gamma2, beta2, nullptr, out2b, 512);

  // ================= FFN =================
  gemm8_k<true, false><<<256, 512, 0, stream>>>(
      out2b, 512, wff1t, 512, ffh, 2048, bff1, 512, 8, nullptr, 0);
  gemm_ln_k<bf16><<<256, 512, 0, stream>>>(
      ffh, 2048, wff2t, bff2, out2b, gamma3, beta3, out3, nullptr, 2048);
}

// Round 12
// 347.190 us; speedup vs baseline: 1.1373x; 1.0235x over previous
//
#include <hip/hip_runtime.h>
#include <hip/hip_bf16.h>

// DecoderLayer: B=8, T=S=1024, D=512, H=8, depth=64, F=2048. fp32 in/out.
// Outputs (concat in d_out): out3 [8,1024,512], sa_w [64,1024,1024], ca_w [64,1024,1024].
// Round 12: gemm_ln upgraded to counted-vmcnt schedule + 2-bit granule XOR
// swizzle (8-way -> 4-way LDS conflicts); 5 deferred weight transposes moved
// into the attn_gemm grid (overlap with self-attention). 9 nodes.

using bf16 = __hip_bfloat16;
typedef __attribute__((ext_vector_type(8))) short bf16x8v;
typedef __attribute__((ext_vector_type(4))) float f32x4;
typedef __attribute__((ext_vector_type(2))) float f32x2;
typedef __attribute__((ext_vector_type(2))) unsigned int u32x2;

#define DEVI __device__ __forceinline__

// 0.125 (1/sqrt(depth)) * log2(e): logits computed directly in exp2 units.
#define QSCL 0.18033688011112042f

DEVI short f2bs(float f) {
  bf16 h = __float2bfloat16(f);
  return *reinterpret_cast<short*>(&h);
}
DEVI bf16 f2b(float f) { return __float2bfloat16(f); }
DEVI float ex2(float x) { return __builtin_amdgcn_exp2f(x); }
DEVI float ldf(const float* p) { return *p; }
DEVI float ldf(const bf16* p) { return __bfloat162float(*p); }

DEVI void gload16(const bf16* g, bf16* l) {
  __builtin_amdgcn_global_load_lds(
      (const __attribute__((address_space(1))) void*)g,
      (__attribute__((address_space(3))) void*)l, 16, 0, 0);
}

// wave-uniform counted vmcnt wait (immediates only)
DEVI void vmwait(int n) {
  if (n == 0)       asm volatile("s_waitcnt vmcnt(0)" ::: "memory");
  else if (n == 1)  asm volatile("s_waitcnt vmcnt(1)" ::: "memory");
  else if (n == 2)  asm volatile("s_waitcnt vmcnt(2)" ::: "memory");
  else if (n == 4)  asm volatile("s_waitcnt vmcnt(4)" ::: "memory");
  else if (n == 5)  asm volatile("s_waitcnt vmcnt(5)" ::: "memory");
  else if (n == 6)  asm volatile("s_waitcnt vmcnt(6)" ::: "memory");
  else if (n == 8)  asm volatile("s_waitcnt vmcnt(8)" ::: "memory");
  else              asm volatile("s_waitcnt vmcnt(10)" ::: "memory");
}
#define SBAR() __builtin_amdgcn_sched_barrier(0)

// ---------------- weight transpose body (shared) ----------------
struct WDesc { const float* src; bf16* dst; int K; int N; int toff; float scl; };
struct WPack5 { WDesc d[5]; };

DEVI void wtrans_body(int t, const WPack5& p, float* tile /* [32*33] */) {
  int wi = 0;
#pragma unroll
  for (int i = 1; i < 5; i++)
    if (t >= p.d[i].toff) wi = i;
  const WDesc d = p.d[wi];
  const int lt = t - d.toff;
  const int nx = d.N >> 5;
  const int n0 = (lt % nx) * 32, k0 = (lt / nx) * 32;
  const int tx = threadIdx.x & 31, ty = threadIdx.x >> 5;
#pragma unroll
  for (int i = 0; i < 32; i += 8)
    tile[(ty + i) * 33 + tx] = d.src[(long)(k0 + ty + i) * d.N + n0 + tx] * d.scl;
  __syncthreads();
#pragma unroll
  for (int i = 0; i < 32; i += 8)
    d.dst[(long)(n0 + ty + i) * d.K + k0 + tx] = f2b(tile[tx * 33 + ty + i]);
}

// ---------------- prep: casts + early weight transposes + bias concat ----------
struct PrepPack {
  const float* x; const float* enc; bf16* xb; bf16* encb;
  WPack5 w;
  const float* bsrc[6]; float bscl[6]; float* bdst;
};

__global__ __launch_bounds__(256) void prep_k(PrepPack p) {
  const int bid = blockIdx.x;
  if (bid < 8192) {
    const float* s = (bid < 4096) ? p.x : p.enc;
    bf16* d = (bid < 4096) ? p.xb : p.encb;
    long i = ((long)(bid & 4095) * 256 + threadIdx.x) * 4;
    f32x4 v = *reinterpret_cast<const f32x4*>(s + i);
    union { short sh[4]; long l; } u;
    u.sh[0] = f2bs(v[0]); u.sh[1] = f2bs(v[1]); u.sh[2] = f2bs(v[2]); u.sh[3] = f2bs(v[3]);
    *reinterpret_cast<long*>(d + i) = u.l;
    return;
  }
  if (bid < 9472) {
    __shared__ float tile[32 * 33];
    wtrans_body(bid - 8192, p.w, tile);
    return;
  }
  const int i = bid - 9472;
  const int e = threadIdx.x * 2;
  f32x2 v = *reinterpret_cast<const f32x2*>(p.bsrc[i] + e);
  v[0] *= p.bscl[i]; v[1] *= p.bscl[i];
  *reinterpret_cast<f32x2*>(p.bdst + i * 512 + e) = v;
}

// ---------------- GEMM body (128^2, shared) ------------
template <int FM, int FN, typename TC, bool RELU, bool VTOUT>
DEVI void gemm_body(int bid, int nblocks,
                    const bf16* __restrict__ A, int lda,
                    const bf16* __restrict__ Bt, int ldb,
                    TC* __restrict__ C, int ldc,
                    const float* __restrict__ bias, int K, int tiles_n,
                    bf16* sA, bf16* sB,
                    bf16* __restrict__ vtout, int vcol0) {
  constexpr int BM = 32 * FM, BN = 32 * FN;
  const int tm8 = (nblocks / tiles_n) >> 3;
  const int r8 = bid >> 3;
  const int tm = (bid & 7) + ((r8 % tm8) << 3);
  const int tn = r8 / tm8;
  const int tid = threadIdx.x, wave = tid >> 6, lane = tid & 63;
  const int wr = wave >> 1, wc = wave & 1;
  const int l16 = lane & 15, lhi = lane >> 4;
  const int srow = lane >> 2, scol = (lane & 3) * 8;

  const bf16* Ab = A + (long)(tm * BM + wave * (BM / 4) + srow) * lda + scol;
  const bf16* Bb = Bt + (long)(tn * BN + wave * (BN / 4) + srow) * ldb + scol;

  auto stage = [&](int buf, int k0) {
#pragma unroll
    for (int i = 0; i < BM / 64; i++)
      gload16(Ab + (long)(i * 16) * lda + k0, sA + buf * BM * 32 + (wave * (BM / 4) + i * 16) * 32);
#pragma unroll
    for (int i = 0; i < BN / 64; i++)
      gload16(Bb + (long)(i * 16) * ldb + k0, sB + buf * BN * 32 + (wave * (BN / 4) + i * 16) * 32);
  };

  stage(0, 0);
  __syncthreads();

  f32x4 acc[FM][FN] = {};
  int cur = 0;
  for (int k0 = 0; k0 < K; k0 += 32) {
    if (k0 + 32 < K) stage(cur ^ 1, k0 + 32);
    bf16x8v af[FM], bfr[FN];
#pragma unroll
    for (int m = 0; m < FM; m++)
      af[m] = *reinterpret_cast<const bf16x8v*>(
          sA + cur * BM * 32 + (wr * 16 * FM + m * 16 + l16) * 32 + lhi * 8);
#pragma unroll
    for (int n = 0; n < FN; n++)
      bfr[n] = *reinterpret_cast<const bf16x8v*>(
          sB + cur * BN * 32 + (wc * 16 * FN + n * 16 + l16) * 32 + lhi * 8);
#pragma unroll
    for (int m = 0; m < FM; m++)
#pragma unroll
      for (int n = 0; n < FN; n++)
        acc[m][n] = __builtin_amdgcn_mfma_f32_16x16x32_bf16(af[m], bfr[n], acc[m][n], 0, 0, 0);
    if (k0 + 32 < K) {
      __syncthreads();
      cur ^= 1;
    }
  }

#pragma unroll
  for (int m = 0; m < FM; m++) {
    const int gr0 = tm * BM + wr * 16 * FM + m * 16 + lhi * 4;
#pragma unroll
    for (int n = 0; n < FN; n++) {
      const int gc = tn * BN + wc * 16 * FN + n * 16 + l16;
      const float bv = bias ? bias[gc] : 0.f;
      if (VTOUT && gc >= vcol0) {
        const int vc = gc - vcol0;
        bf16* vdst = vtout + ((long)(((gr0 >> 10) << 3) + (vc >> 6)) << 16)
                           + ((long)(vc & 63) << 10) + (gr0 & 1023);
        union { short sh[4]; u32x2 u2; } pk;
#pragma unroll
        for (int j = 0; j < 4; j++) pk.sh[j] = f2bs(acc[m][n][j] + bv);
        *reinterpret_cast<u32x2*>(vdst) = pk.u2;
      } else {
#pragma unroll
        for (int j = 0; j < 4; j++) {
          float v = acc[m][n][j] + bv;
          if (RELU) v = fmaxf(v, 0.f);
          if constexpr (sizeof(TC) == 4)
            C[(long)(gr0 + j) * ldc + gc] = v;
          else
            C[(long)(gr0 + j) * ldc + gc] = f2b(v);
        }
      }
    }
  }
}

template <int FM, int FN, typename TC, bool RELU>
__global__ __launch_bounds__(256) void gemm_gl_k(
    const bf16* __restrict__ A, int lda, const bf16* __restrict__ Bt, int ldb,
    TC* __restrict__ C, int ldc, const float* __restrict__ bias, int K, int tiles_n) {
  __shared__ bf16 sA[2 * 32 * FM * 32];
  __shared__ bf16 sB[2 * 32 * FN * 32];
  gemm_body<FM, FN, TC, RELU, false>(blockIdx.x, gridDim.x, A, lda, Bt, ldb, C, ldc,
                                     bias, K, tiles_n, sA, sB, nullptr, 0);
}

// ---------------- gemm8_k: 256^2 tile, BK=64, 8 waves, swizzled LDS, counted vmcnt
template <bool RELU, bool VTOUT>
__global__ __launch_bounds__(512, 2) void gemm8_k(
    const bf16* __restrict__ A, int lda, const bf16* __restrict__ Bt, int ldb,
    bf16* __restrict__ C, int ldc, const float* __restrict__ bias, int K, int tiles_n,
    bf16* __restrict__ vtout, int vcol0) {
  __shared__ bf16 sA[2][256 * 64];
  __shared__ bf16 sB[2][256 * 64];
  const int NKT = K >> 6;
  const int bid = blockIdx.x;
  const int tm8 = ((int)gridDim.x / tiles_n) >> 3;
  const int r8 = bid >> 3;
  const int tm = (bid & 7) + ((r8 % tm8) << 3);
  const int tn = r8 / tm8;
  const int tid = threadIdx.x, wave = tid >> 6, lane = tid & 63;
  const int wm = wave >> 2, wn = wave & 3;
  const int l16 = lane & 15, lhi = lane >> 4;

  const int srow = tid >> 3;
  const int scol = ((tid & 7) ^ (srow & 7)) * 8;
  const bf16* Ag = A + (long)(tm * 256 + srow) * lda + scol;
  const bf16* Bg = Bt + (long)(tn * 256 + srow) * ldb + scol;

  auto stage = [&](int buf, int kt) {
    const int kofs = kt * 64;
#pragma unroll
    for (int p = 0; p < 4; p++)
      gload16(Ag + (long)(p * 64) * lda + kofs, &sA[buf][(p * 64 + wave * 8) * 64]);
#pragma unroll
    for (int p = 0; p < 4; p++)
      gload16(Bg + (long)(p * 64) * ldb + kofs, &sB[buf][(p * 64 + wave * 8) * 64]);
  };

  stage(0, 0);
  if (NKT > 1) stage(1, 1);

  f32x4 acc[8][4] = {};
  const int sxor = (l16 & 7) << 4;
  const int aoff0 = ((lhi * 16) ^ sxor) >> 1;
  const int aoff1 = ((64 + lhi * 16) ^ sxor) >> 1;

#pragma unroll 1
  for (int kt = 0; kt < NKT; kt++) {
    const int buf = kt & 1;
    vmwait((kt + 1 < NKT) ? 8 : 0);
    SBAR();
    __builtin_amdgcn_s_barrier();
    SBAR();
#pragma unroll
    for (int ks = 0; ks < 2; ks++) {
      const int ao = ks ? aoff1 : aoff0;
      bf16x8v bfr[4];
#pragma unroll
      for (int n = 0; n < 4; n++)
        bfr[n] = *reinterpret_cast<const bf16x8v*>(
            &sB[buf][(wn * 64 + n * 16 + l16) * 64 + ao]);
#pragma unroll
      for (int mh = 0; mh < 2; mh++) {
        bf16x8v af[4];
#pragma unroll
        for (int mm = 0; mm < 4; mm++)
          af[mm] = *reinterpret_cast<const bf16x8v*>(
              &sA[buf][(wm * 128 + (mh * 4 + mm) * 16 + l16) * 64 + ao]);
        __builtin_amdgcn_s_setprio(1);
#pragma unroll
        for (int mm = 0; mm < 4; mm++)
#pragma unroll
          for (int n = 0; n < 4; n++)
            acc[mh * 4 + mm][n] = __builtin_amdgcn_mfma_f32_16x16x32_bf16(
                af[mm], bfr[n], acc[mh * 4 + mm][n], 0, 0, 0);
        __builtin_amdgcn_s_setprio(0);
      }
    }
    SBAR();
    __builtin_amdgcn_s_barrier();
    SBAR();
    if (kt + 2 < NKT) stage(buf, kt + 2);
  }

#pragma unroll
  for (int m = 0; m < 8; m++) {
    const int gr0 = tm * 256 + wm * 128 + m * 16 + lhi * 4;
#pragma unroll
    for (int n = 0; n < 4; n++) {
      const int gc = tn * 256 + wn * 64 + n * 16 + l16;
      const float bv = bias[gc];
      if (VTOUT && gc >= vcol0) {
        const int vc = gc - vcol0;
        bf16* vdst = vtout + ((long)(((gr0 >> 10) << 3) + (vc >> 6)) << 16)
                           + ((long)(vc & 63) << 10) + (gr0 & 1023);
        union { short sh[4]; u32x2 u2; } pk;
#pragma unroll
        for (int j = 0; j < 4; j++) pk.sh[j] = f2bs(acc[m][n][j] + bv);
        *reinterpret_cast<u32x2*>(vdst) = pk.u2;
      } else {
#pragma unroll
        for (int j = 0; j < 4; j++) {
          float v = acc[m][n][j] + bv;
          if (RELU) v = fmaxf(v, 0.f);
          C[(long)(gr0 + j) * ldc + gc] = f2b(v);
        }
      }
    }
  }
}

// ---------------- attention body: counted-vmcnt pipelined 2-pass flash ----------
// (round-8 verified version) LDS 34816 B: Kst[3][2048] | Vst[3][2048] | pst[4][1280]
template <bool CAUSAL>
DEVI void attn_body(int bid, char* smem,
                    const bf16* __restrict__ Qm, int ldq,
                    const bf16* __restrict__ Km, int ldk,
                    const bf16* __restrict__ vt,
                    float* __restrict__ P, bf16* __restrict__ ctx) {
  bf16* Kst = (bf16*)smem;      // 3 x 2048 elems
  bf16* Vst = Kst + 3 * 2048;   // 3 x 2048
  bf16* pst = Vst + 3 * 2048;   // 4 x 1280
  const int bh = bid & 63;
  const int g = bid >> 6;
  const int qx = CAUSAL ? ((g < 4) ? g : 11 - g) : g;  // anti-correlated pairs
  const int b = bh >> 3, h = bh & 7;
  const int tid = threadIdx.x, wave = tid >> 6, lane = tid & 63;
  const int l16 = lane & 15, lhi = lane >> 4;
  const int q0 = qx * 128 + wave * 32;
  const bf16* Qb = Qm + (long)(b * 1024 + q0) * ldq + h * 64;
  const bf16* Kb = Km + (long)b * 1024 * ldk + h * 64;
  const bf16* Vb = vt + (long)bh * 64 * 1024;

  const int nun = CAUSAL ? (q0 >> 5) : 32;
  const int nchw = CAUSAL ? nun + 1 : 32;
  const int nchb = CAUSAL ? qx * 4 + 4 : 32;

  const bf16* ksrc = Kb + (long)(tid >> 3) * ldk + ((tid & 7) ^ ((tid >> 3) & 7)) * 8;
  const bf16* vsrc = Vb + (long)(tid >> 2) * 1024 + ((tid & 3) ^ ((tid >> 2) & 3)) * 8;

  int kfo[2][2];
#pragma unroll
  for (int cc = 0; cc < 2; cc++) {
    const int r = cc * 16 + l16;
#pragma unroll
    for (int ks = 0; ks < 2; ks++)
      kfo[cc][ks] = r * 64 + (((ks * 64 + lhi * 16) ^ ((r & 7) << 4)) >> 1);
  }
  int vfo[4];
#pragma unroll
  for (int n = 0; n < 4; n++) {
    const int r = n * 16 + l16;
    vfo[n] = r * 32 + (((lhi * 16) ^ ((r & 3) << 4)) >> 1);
  }

  bf16x8v qB[2][2];
#pragma unroll
  for (int m = 0; m < 2; m++)
#pragma unroll
    for (int ks = 0; ks < 2; ks++)
      qB[m][ks] = *reinterpret_cast<const bf16x8v*>(
          Qb + (long)(m * 16 + l16) * ldq + ks * 32 + lhi * 8);

  float ll[2] = {0.f, 0.f};

  // ================ pass 1: l-sum only (no max), K triple-buffered ================
  gload16(ksrc, Kst + wave * 512);
  gload16(ksrc + (long)32 * ldk, Kst + 2048 + wave * 512);
#pragma unroll 1
  for (int ch = 0; ch < nchb; ch++) {
    if (ch + 1 < nchb) vmwait(1); else vmwait(0);
    SBAR();
    __builtin_amdgcn_s_barrier();
    SBAR();
    if (ch + 2 < nchb)
      gload16(ksrc + (long)(ch + 2) * 32 * ldk, Kst + ((ch + 2) % 3) * 2048 + wave * 512);
    if (ch < nchw) {
      const int bo = (ch % 3) * 2048;
      bf16x8v kf[2][2];
#pragma unroll
      for (int cc = 0; cc < 2; cc++)
#pragma unroll
        for (int ks = 0; ks < 2; ks++)
          kf[cc][ks] = *reinterpret_cast<const bf16x8v*>(&Kst[bo + kfo[cc][ks]]);
      const bool diag = CAUSAL && (ch == nun);
#pragma unroll
      for (int m = 0; m < 2; m++) {
        f32x4 s0 = {}, s1 = {};
        s0 = __builtin_amdgcn_mfma_f32_16x16x32_bf16(kf[0][0], qB[m][0], s0, 0, 0, 0);
        s0 = __builtin_amdgcn_mfma_f32_16x16x32_bf16(kf[0][1], qB[m][1], s0, 0, 0, 0);
        s1 = __builtin_amdgcn_mfma_f32_16x16x32_bf16(kf[1][0], qB[m][0], s1, 0, 0, 0);
        s1 = __builtin_amdgcn_mfma_f32_16x16x32_bf16(kf[1][1], qB[m][1], s1, 0, 0, 0);
        if (diag) {
          const int rq = m * 16 + l16;
#pragma unroll
          for (int j = 0; j < 4; j++) {
            s0[j] = (lhi * 4 + j <= rq) ? s0[j] : -1e30f;   // exp2 -> 0 exactly
            s1[j] = (16 + lhi * 4 + j <= rq) ? s1[j] : -1e30f;
          }
        }
        float sum = 0.f;
#pragma unroll
        for (int j = 0; j < 4; j++) sum += ex2(s0[j]) + ex2(s1[j]);
        ll[m] += sum;
      }
    }
  }
  __syncthreads();  // pass boundary

  float il[2];
#pragma unroll
  for (int m = 0; m < 2; m++) {
    float lo = ll[m];
    lo += __shfl_xor(lo, 16);
    lo += __shfl_xor(lo, 32);
    il[m] = 1.f / lo;
  }

  // ================ pass 2: P write + PV, K+V triple-buffered ================
  f32x4 pv[2][4] = {};
  float* Pg = P + (long)bh * 1024 * 1024 + (long)q0 * 1024;
  gload16(ksrc, Kst + wave * 512);
  gload16(vsrc, Vst + wave * 512);
  gload16(ksrc + (long)32 * ldk, Kst + 2048 + wave * 512);
  gload16(vsrc + 32, Vst + 2048 + wave * 512);
#pragma unroll 1
  for (int ch = 0; ch < nchb; ch++) {
    const int Sa = (ch >= 2 && ch - 2 < nchw) ? 4 : 0;
    const int Lr = (ch + 1 < nchb) ? 2 : 0;
    const int Sb = (ch >= 1 && ch - 1 < nchw) ? 4 : 0;
    vmwait(Sa + Lr + Sb);
    SBAR();
    __builtin_amdgcn_s_barrier();
    SBAR();
    if (ch + 2 < nchb) {
      gload16(ksrc + (long)(ch + 2) * 32 * ldk, Kst + ((ch + 2) % 3) * 2048 + wave * 512);
      gload16(vsrc + (ch + 2) * 32, Vst + ((ch + 2) % 3) * 2048 + wave * 512);
    }
    if (ch < nchw) {
      const int kc = ch * 32;
      const int bo = (ch % 3) * 2048;
      bf16x8v kf[2][2], vf[4];
#pragma unroll
      for (int cc = 0; cc < 2; cc++)
#pragma unroll
        for (int ks = 0; ks < 2; ks++)
          kf[cc][ks] = *reinterpret_cast<const bf16x8v*>(&Kst[bo + kfo[cc][ks]]);
#pragma unroll
      for (int n = 0; n < 4; n++)
        vf[n] = *reinterpret_cast<const bf16x8v*>(&Vst[bo + vfo[n]]);
      const bool diag = CAUSAL && (ch == nun);
#pragma unroll
      for (int m = 0; m < 2; m++) {
        f32x4 s0 = {}, s1 = {};
        s0 = __builtin_amdgcn_mfma_f32_16x16x32_bf16(kf[0][0], qB[m][0], s0, 0, 0, 0);
        s0 = __builtin_amdgcn_mfma_f32_16x16x32_bf16(kf[0][1], qB[m][1], s0, 0, 0, 0);
        s1 = __builtin_amdgcn_mfma_f32_16x16x32_bf16(kf[1][0], qB[m][0], s1, 0, 0, 0);
        s1 = __builtin_amdgcn_mfma_f32_16x16x32_bf16(kf[1][1], qB[m][1], s1, 0, 0, 0);
        if (diag) {
          const int rq = m * 16 + l16;
#pragma unroll
          for (int j = 0; j < 4; j++) {
            s0[j] = (lhi * 4 + j <= rq) ? s0[j] : -1e30f;
            s1[j] = (16 + lhi * 4 + j <= rq) ? s1[j] : -1e30f;
          }
        }
        f32x4 p0, p1;
#pragma unroll
        for (int j = 0; j < 4; j++) {
          p0[j] = ex2(s0[j]) * il[m];
          p1[j] = ex2(s1[j]) * il[m];
        }
        const int prow = (m * 16 + l16) * 40;
        union { short s[4]; u32x2 u; } pk0, pk1;
#pragma unroll
        for (int j = 0; j < 4; j++) { pk0.s[j] = f2bs(p0[j]); pk1.s[j] = f2bs(p1[j]); }
        *reinterpret_cast<u32x2*>(&pst[wave * 1280 + prow + lhi * 4]) = pk0.u;
        *reinterpret_cast<u32x2*>(&pst[wave * 1280 + prow + 16 + lhi * 4]) = pk1.u;
      }
#pragma unroll
      for (int m = 0; m < 2; m++) {
        bf16x8v pa = *reinterpret_cast<const bf16x8v*>(
            &pst[wave * 1280 + (m * 16 + l16) * 40 + lhi * 8]);
#pragma unroll
        for (int n = 0; n < 4; n++)
          pv[m][n] = __builtin_amdgcn_mfma_f32_16x16x32_bf16(pa, vf[n], pv[m][n], 0, 0, 0);
      }
      // flush P from pst (bf16 -> f32 bitshift): 4 nt-stores, 8 rows x 128B each
#pragma unroll
      for (int f = 0; f < 4; f++) {
        const int row = f * 8 + (lane >> 3);
        u32x2 raw = *reinterpret_cast<const u32x2*>(
            &pst[wave * 1280 + row * 40 + (lane & 7) * 4]);
        union { unsigned int u; float fl; } c0, c1, c2, c3;
        c0.u = raw[0] << 16; c1.u = raw[0] & 0xffff0000u;
        c2.u = raw[1] << 16; c3.u = raw[1] & 0xffff0000u;
        f32x4 val = {c0.fl, c1.fl, c2.fl, c3.fl};
        __builtin_nontemporal_store(
            val, reinterpret_cast<f32x4*>(Pg + (long)row * 1024 + kc + (lane & 7) * 4));
      }
    }
  }

  bf16* cb = ctx + (long)(b * 1024 + q0) * 512 + h * 64;
#pragma unroll
  for (int m = 0; m < 2; m++)
#pragma unroll
    for (int n = 0; n < 4; n++)
#pragma unroll
      for (int j = 0; j < 4; j++)
        cb[(long)(m * 16 + lhi * 4 + j) * 512 + n * 16 + l16] = f2b(pv[m][n][j]);
}

template <bool CAUSAL>
__global__ __launch_bounds__(256) void attn_k(
    const bf16* __restrict__ Qm, int ldq, const bf16* __restrict__ Km, int ldk,
    const bf16* __restrict__ vt, float* __restrict__ P, bf16* __restrict__ ctx) {
  __shared__ __align__(16) char smem[34816];
  attn_body<CAUSAL>(blockIdx.x, smem, Qm, ldq, Km, ldk, vt, P, ctx);
}

// merged: 0..511 self-attn, 512..1023 kv2 GEMM (+fused vt2), 1024+ deferred
// weight transposes (independent; consumed only by later nodes).
__global__ __launch_bounds__(256) void attn_gemm_k(
    const bf16* __restrict__ Qm, int ldq, const bf16* __restrict__ Km, int ldk,
    const bf16* __restrict__ vt, float* __restrict__ P, bf16* __restrict__ ctx,
    const bf16* __restrict__ A, int lda, const bf16* __restrict__ Bt, int ldb,
    bf16* __restrict__ C, int ldc, const float* __restrict__ bias, int K, int tiles_n,
    bf16* __restrict__ vt2, WPack5 wp) {
  __shared__ __align__(16) char smem[34816];
  if (blockIdx.x < 512) {
    attn_body<true>(blockIdx.x, smem, Qm, ldq, Km, ldk, vt, P, ctx);
  } else if (blockIdx.x < 1024) {
    bf16* sA = (bf16*)smem;
    gemm_body<4, 4, bf16, false, true>(blockIdx.x - 512, 512, A, lda, Bt, ldb,
                                       C, ldc, bias, K, tiles_n, sA, sA + 8192,
                                       vt2, 512);
  } else {
    wtrans_body((int)blockIdx.x - 1024, wp, (float*)smem);
  }
}

// ---------------- GEMM + residual add + LayerNorm fused epilogue ----------------
// Counted-vmcnt schedule + 2-bit granule XOR swizzle (4-way LDS, was 8-way).
template <typename TR>
__global__ __launch_bounds__(512) void gemm_ln_k(
    const bf16* __restrict__ A, int lda, const bf16* __restrict__ Bt,
    const float* __restrict__ bias, const TR* __restrict__ resid,
    const float* __restrict__ gamma, const float* __restrict__ beta,
    float* __restrict__ outf, bf16* __restrict__ outb, int K) {
  __shared__ bf16 sA[2][32 * 32];
  __shared__ bf16 sB[2][512 * 32];
  __shared__ float red[2][32][8];
  __shared__ f32x2 mr[32];
  const int tm = blockIdx.x;
  const int tid = threadIdx.x, wave = tid >> 6, lane = tid & 63;
  const int l16 = lane & 15, lhi = lane >> 4;

  // staging: linear LDS dest (DMA), pre-swizzled global source granule
  const int srow = tid >> 2;
  const int sgran = ((tid & 3) ^ (srow & 3)) * 8;
  const bf16* Asrc = A + (long)(tm * 32 + srow) * lda + sgran;
  const bf16* Bsrc = Bt + (long)srow * K + sgran;

  auto stage = [&](int buf, int kt) {
    const int k0 = kt * 32;
    if (tid < 128) gload16(Asrc + k0, &sA[buf][(tid >> 6) * 512]);
#pragma unroll
    for (int p = 0; p < 4; p++)
      gload16(Bsrc + (long)(p * 128) * K + k0, &sB[buf][p * 4096 + wave * 512]);
  };

  const int NK = K >> 5;
  stage(0, 0);
  if (NK > 1) stage(1, 1);
  const int W = (wave < 2) ? 5 : 4;  // waves 0-1 also stage A

  f32x4 acc[2][4] = {};
#pragma unroll 1
  for (int kt = 0; kt < NK; kt++) {
    const int buf = kt & 1;
    vmwait((kt + 1 < NK) ? W : 0);
    SBAR();
    __builtin_amdgcn_s_barrier();
    SBAR();
    bf16x8v af[2], bfr[4];
#pragma unroll
    for (int m = 0; m < 2; m++) {
      const int r = m * 16 + l16;
      af[m] = *reinterpret_cast<const bf16x8v*>(&sA[buf][r * 32 + ((lhi ^ (r & 3)) * 8)]);
    }
#pragma unroll
    for (int n = 0; n < 4; n++) {
      const int r = wave * 64 + n * 16 + l16;
      bfr[n] = *reinterpret_cast<const bf16x8v*>(&sB[buf][r * 32 + ((lhi ^ (r & 3)) * 8)]);
    }
    __builtin_amdgcn_s_setprio(1);
#pragma unroll
    for (int m = 0; m < 2; m++)
#pragma unroll
      for (int n = 0; n < 4; n++)
        acc[m][n] = __builtin_amdgcn_mfma_f32_16x16x32_bf16(af[m], bfr[n], acc[m][n], 0, 0, 0);
    __builtin_amdgcn_s_setprio(0);
    SBAR();
    __builtin_amdgcn_s_barrier();    // all waves done reading buf -> WAR-safe
    SBAR();
    if (kt + 2 < NK) stage(buf, kt + 2);
  }

  float bv[4], gm[4], bt[4];
#pragma unroll
  for (int n = 0; n < 4; n++) {
    const int gc = wave * 64 + n * 16 + l16;
    bv[n] = bias[gc]; gm[n] = gamma[gc]; bt[n] = beta[gc];
  }
  float v[2][4][4], rs[2][4], rq[2][4];
#pragma unroll
  for (int m = 0; m < 2; m++)
#pragma unroll
    for (int j = 0; j < 4; j++) { rs[m][j] = 0.f; rq[m][j] = 0.f; }
#pragma unroll
  for (int m = 0; m < 2; m++) {
#pragma unroll
    for (int j = 0; j < 4; j++) {
      const long grow = tm * 32 + m * 16 + lhi * 4 + j;
#pragma unroll
      for (int n = 0; n < 4; n++) {
        const int gc = wave * 64 + n * 16 + l16;
        const float val = acc[m][n][j] + bv[n] + ldf(resid + grow * 512 + gc);
        v[m][n][j] = val;
        rs[m][j] += val;
        rq[m][j] += val * val;
      }
    }
  }
#pragma unroll
  for (int m = 0; m < 2; m++)
#pragma unroll
    for (int j = 0; j < 4; j++)
#pragma unroll
      for (int off = 1; off <= 8; off <<= 1) {
        rs[m][j] += __shfl_xor(rs[m][j], off);
        rq[m][j] += __shfl_xor(rq[m][j], off);
      }
  if (l16 == 0) {
#pragma unroll
    for (int m = 0; m < 2; m++)
#pragma unroll
      for (int j = 0; j < 4; j++) {
        red[0][m * 16 + lhi * 4 + j][wave] = rs[m][j];
        red[1][m * 16 + lhi * 4 + j][wave] = rq[m][j];
      }
  }
  __syncthreads();
  if (tid < 32) {
    float s = 0.f, q = 0.f;
#pragma unroll
    for (int w = 0; w < 8; w++) { s += red[0][tid][w]; q += red[1][tid][w]; }
    const float mean = s * (1.f / 512.f);
    const float var = q * (1.f / 512.f) - mean * mean;
    f32x2 o = {mean, rsqrtf(var + 1e-5f)};
    mr[tid] = o;
  }
  __syncthreads();
#pragma unroll
  for (int m = 0; m < 2; m++) {
#pragma unroll
    for (int j = 0; j < 4; j++) {
      const int row = m * 16 + lhi * 4 + j;
      const f32x2 mrv = mr[row];
      const long grow = tm * 32 + row;
#pragma unroll
      for (int n = 0; n < 4; n++) {
        const int gc = wave * 64 + n * 16 + l16;
        const float o = (v[m][n][j] - mrv[0]) * mrv[1] * gm[n] + bt[n];
        if (outf) outf[grow * 512 + gc] = o;
        if (outb) outb[grow * 512 + gc] = f2b(o);
      }
    }
  }
}

extern "C" void kernel_launch(void* const* d_in, const int* in_sizes, int n_in,
                              void* d_out, int out_size, void* d_ws, size_t ws_size,
                              hipStream_t stream) {
  const float* x = (const float*)d_in[0];
  const float* enc = (const float*)d_in[1];
  const float* wq1 = (const float*)d_in[4];  const float* bq1 = (const float*)d_in[5];
  const float* wk1 = (const float*)d_in[6];  const float* bk1 = (const float*)d_in[7];
  const float* wv1 = (const float*)d_in[8];  const float* bv1 = (const float*)d_in[9];
  const float* wo1 = (const float*)d_in[10]; const float* bo1 = (const float*)d_in[11];
  const float* wq2 = (const float*)d_in[12]; const float* bq2 = (const float*)d_in[13];
  const float* wk2 = (const float*)d_in[14]; const float* bk2 = (const float*)d_in[15];
  const float* wv2 = (const float*)d_in[16]; const float* bv2 = (const float*)d_in[17];
  const float* wo2 = (const float*)d_in[18]; const float* bo2 = (const float*)d_in[19];
  const float* wff1 = (const float*)d_in[20]; const float* bff1 = (const float*)d_in[21];
  const float* wff2 = (const float*)d_in[22]; const float* bff2 = (const float*)d_in[23];
  const float* gamma1 = (const float*)d_in[24]; const float* beta1 = (const float*)d_in[25];
  const float* gamma2 = (const float*)d_in[26]; const float* beta2 = (const float*)d_in[27];
  const float* gamma3 = (const float*)d_in[28]; const float* beta3 = (const float*)d_in[29];

  float* out3 = (float*)d_out;
  float* sa_w = out3 + (long)8 * 1024 * 512;
  float* ca_w = sa_w + (long)64 * 1024 * 1024;

  char* w = (char*)d_ws;
  auto alloc = [&](long bytes) { char* p = w; w += (bytes + 255) & ~255L; return p; };
  bf16* xb     = (bf16*)alloc(8192L * 512 * 2);
  bf16* encb   = (bf16*)alloc(8192L * 512 * 2);
  bf16* wqkv1t = (bf16*)alloc(1536L * 512 * 2);
  bf16* wo1t   = (bf16*)alloc(512L * 512 * 2);
  bf16* wq2t   = (bf16*)alloc(512L * 512 * 2);
  bf16* wkv2t  = (bf16*)alloc(1024L * 512 * 2);
  bf16* wo2t   = (bf16*)alloc(512L * 512 * 2);
  bf16* wff1t  = (bf16*)alloc(2048L * 512 * 2);
  bf16* wff2t  = (bf16*)alloc(512L * 2048 * 2);
  float* bcat  = (float*)alloc(3072L * 4);  // bq1*S | bk1 | bv1 | bk2 | bv2 | bq2*S
  bf16* qkv    = (bf16*)alloc(8192L * 1536 * 2);
  bf16* q2b    = (bf16*)alloc(8192L * 512 * 2);
  bf16* kv2    = (bf16*)alloc(8192L * 1024 * 2);
  bf16* vt     = (bf16*)alloc(64L * 64 * 1024 * 2);
  bf16* vt2    = (bf16*)alloc(64L * 64 * 1024 * 2);
  bf16* ctx    = (bf16*)alloc(8192L * 512 * 2);
  bf16* out1b  = (bf16*)alloc(8192L * 512 * 2);
  bf16* out2b  = (bf16*)alloc(8192L * 512 * 2);
  bf16* ffh    = qkv;  // alias: qkv + q2b dead by FFN; spans 32MB

  // ---- prep (casts + early weights + bias) ----
  PrepPack pp;
  pp.x = x; pp.enc = enc; pp.xb = xb; pp.encb = encb;
  pp.w.d[0] = {wq1, wqkv1t,               512, 512, 0,    QSCL};
  pp.w.d[1] = {wk1, wqkv1t + 512L * 512,  512, 512, 256,  1.f};
  pp.w.d[2] = {wv1, wqkv1t + 1024L * 512, 512, 512, 512,  1.f};
  pp.w.d[3] = {wk2, wkv2t,                512, 512, 768,  1.f};
  pp.w.d[4] = {wv2, wkv2t + 512L * 512,   512, 512, 1024, 1.f};
  pp.bsrc[0] = bq1; pp.bsrc[1] = bk1; pp.bsrc[2] = bv1;
  pp.bsrc[3] = bk2; pp.bsrc[4] = bv2; pp.bsrc[5] = bq2;
  pp.bscl[0] = QSCL; pp.bscl[1] = 1.f; pp.bscl[2] = 1.f;
  pp.bscl[3] = 1.f;  pp.bscl[4] = 1.f; pp.bscl[5] = QSCL;
  pp.bdst = bcat;
  prep_k<<<9478, 256, 0, stream>>>(pp);

  // deferred weight transposes (overlap with self-attention)
  WPack5 wd;
  wd.d[0] = {wo1,  wo1t,  512,  512,  0,    1.f};
  wd.d[1] = {wq2,  wq2t,  512,  512,  256,  QSCL};
  wd.d[2] = {wo2,  wo2t,  512,  512,  512,  1.f};
  wd.d[3] = {wff1, wff1t, 512,  2048, 768,  1.f};
  wd.d[4] = {wff2, wff2t, 2048, 512,  1792, 1.f};

  // ================= self attention (+ overlapped kv2 + weight prep) ========
  gemm8_k<false, true><<<192, 512, 0, stream>>>(
      xb, 512, wqkv1t, 512, qkv, 1536, bcat, 512, 6, vt, 1024);  // V -> vt fused
  attn_gemm_k<<<3840, 256, 0, stream>>>(
      qkv, 1536, qkv + 512, 1536, vt, sa_w, ctx,
      encb, 512, wkv2t, 512, kv2, 1024, bcat + 1536, 512, 8, vt2, wd);
  gemm_ln_k<float><<<256, 512, 0, stream>>>(
      ctx, 512, wo1t, bo1, x, gamma1, beta1, nullptr, out1b, 512);

  // ================= cross attention =================
  gemm_gl_k<2, 4, bf16, false><<<512, 256, 0, stream>>>(
      out1b, 512, wq2t, 512, q2b, 512, bcat + 2560, 512, 4);
  attn_k<false><<<512, 256, 0, stream>>>(
      q2b, 512, kv2, 1024, vt2, ca_w, ctx);
  gemm_ln_k<bf16><<<256, 512, 0, stream>>>(
      ctx, 512, wo2t, bo2, out1b, gamma2, beta2, nullptr, out2b, 512);

  // ================= FFN =================
  gemm8_k<true, false><<<256, 512, 0, stream>>>(
      out2b, 512, wff1t, 512, ffh, 2048, bff1, 512, 8, nullptr, 0);
  gemm_ln_k<bf16><<<256, 512, 0, stream>>>(
      ffh, 2048, wff2t, bff2, out2b, gamma3, beta3, out3, nullptr, 2048);
}

// Round 13
// 344.774 us; speedup vs baseline: 1.1452x; 1.0070x over previous
//
#include <hip/hip_runtime.h>
#include <hip/hip_bf16.h>

// DecoderLayer: B=8, T=S=1024, D=512, H=8, depth=64, F=2048. fp32 in/out.
// Outputs (concat in d_out): out3 [8,1024,512], sa_w [64,1024,1024], ca_w [64,1024,1024].
// Round 13: q2 projection fused into cross-attention (per-block 128x64x512
// mini-GEMM -> swizzled LDS Q-tile -> qB frags -> unchanged attn core).
// Kills q2b round-trip + one node. 8 nodes.

using bf16 = __hip_bfloat16;
typedef __attribute__((ext_vector_type(8))) short bf16x8v;
typedef __attribute__((ext_vector_type(4))) float f32x4;
typedef __attribute__((ext_vector_type(2))) float f32x2;
typedef __attribute__((ext_vector_type(2))) unsigned int u32x2;

#define DEVI __device__ __forceinline__

// 0.125 (1/sqrt(depth)) * log2(e): logits computed directly in exp2 units.
#define QSCL 0.18033688011112042f

DEVI short f2bs(float f) {
  bf16 h = __float2bfloat16(f);
  return *reinterpret_cast<short*>(&h);
}
DEVI bf16 f2b(float f) { return __float2bfloat16(f); }
DEVI float ex2(float x) { return __builtin_amdgcn_exp2f(x); }
DEVI float ldf(const float* p) { return *p; }
DEVI float ldf(const bf16* p) { return __bfloat162float(*p); }

DEVI void gload16(const bf16* g, bf16* l) {
  __builtin_amdgcn_global_load_lds(
      (const __attribute__((address_space(1))) void*)g,
      (__attribute__((address_space(3))) void*)l, 16, 0, 0);
}

// wave-uniform counted vmcnt wait (immediates only)
DEVI void vmwait(int n) {
  if (n == 0)       asm volatile("s_waitcnt vmcnt(0)" ::: "memory");
  else if (n == 1)  asm volatile("s_waitcnt vmcnt(1)" ::: "memory");
  else if (n == 2)  asm volatile("s_waitcnt vmcnt(2)" ::: "memory");
  else if (n == 3)  asm volatile("s_waitcnt vmcnt(3)" ::: "memory");
  else if (n == 4)  asm volatile("s_waitcnt vmcnt(4)" ::: "memory");
  else if (n == 5)  asm volatile("s_waitcnt vmcnt(5)" ::: "memory");
  else if (n == 6)  asm volatile("s_waitcnt vmcnt(6)" ::: "memory");
  else if (n == 8)  asm volatile("s_waitcnt vmcnt(8)" ::: "memory");
  else              asm volatile("s_waitcnt vmcnt(10)" ::: "memory");
}
#define SBAR() __builtin_amdgcn_sched_barrier(0)

// ---------------- weight transpose body (shared) ----------------
struct WDesc { const float* src; bf16* dst; int K; int N; int toff; float scl; };
struct WPack5 { WDesc d[5]; };

DEVI void wtrans_body(int t, const WPack5& p, float* tile /* [32*33] */) {
  int wi = 0;
#pragma unroll
  for (int i = 1; i < 5; i++)
    if (t >= p.d[i].toff) wi = i;
  const WDesc d = p.d[wi];
  const int lt = t - d.toff;
  const int nx = d.N >> 5;
  const int n0 = (lt % nx) * 32, k0 = (lt / nx) * 32;
  const int tx = threadIdx.x & 31, ty = threadIdx.x >> 5;
#pragma unroll
  for (int i = 0; i < 32; i += 8)
    tile[(ty + i) * 33 + tx] = d.src[(long)(k0 + ty + i) * d.N + n0 + tx] * d.scl;
  __syncthreads();
#pragma unroll
  for (int i = 0; i < 32; i += 8)
    d.dst[(long)(n0 + ty + i) * d.K + k0 + tx] = f2b(tile[tx * 33 + ty + i]);
}

// ---------------- prep: casts + early weight transposes + bias concat ----------
struct PrepPack {
  const float* x; const float* enc; bf16* xb; bf16* encb;
  WPack5 w;
  const float* bsrc[6]; float bscl[6]; float* bdst;
};

__global__ __launch_bounds__(256) void prep_k(PrepPack p) {
  const int bid = blockIdx.x;
  if (bid < 8192) {
    const float* s = (bid < 4096) ? p.x : p.enc;
    bf16* d = (bid < 4096) ? p.xb : p.encb;
    long i = ((long)(bid & 4095) * 256 + threadIdx.x) * 4;
    f32x4 v = *reinterpret_cast<const f32x4*>(s + i);
    union { short sh[4]; long l; } u;
    u.sh[0] = f2bs(v[0]); u.sh[1] = f2bs(v[1]); u.sh[2] = f2bs(v[2]); u.sh[3] = f2bs(v[3]);
    *reinterpret_cast<long*>(d + i) = u.l;
    return;
  }
  if (bid < 9472) {
    __shared__ float tile[32 * 33];
    wtrans_body(bid - 8192, p.w, tile);
    return;
  }
  const int i = bid - 9472;
  const int e = threadIdx.x * 2;
  f32x2 v = *reinterpret_cast<const f32x2*>(p.bsrc[i] + e);
  v[0] *= p.bscl[i]; v[1] *= p.bscl[i];
  *reinterpret_cast<f32x2*>(p.bdst + i * 512 + e) = v;
}

// ---------------- GEMM body (128^2, shared) ------------
template <int FM, int FN, typename TC, bool RELU, bool VTOUT>
DEVI void gemm_body(int bid, int nblocks,
                    const bf16* __restrict__ A, int lda,
                    const bf16* __restrict__ Bt, int ldb,
                    TC* __restrict__ C, int ldc,
                    const float* __restrict__ bias, int K, int tiles_n,
                    bf16* sA, bf16* sB,
                    bf16* __restrict__ vtout, int vcol0) {
  constexpr int BM = 32 * FM, BN = 32 * FN;
  const int tm8 = (nblocks / tiles_n) >> 3;
  const int r8 = bid >> 3;
  const int tm = (bid & 7) + ((r8 % tm8) << 3);
  const int tn = r8 / tm8;
  const int tid = threadIdx.x, wave = tid >> 6, lane = tid & 63;
  const int wr = wave >> 1, wc = wave & 1;
  const int l16 = lane & 15, lhi = lane >> 4;
  const int srow = lane >> 2, scol = (lane & 3) * 8;

  const bf16* Ab = A + (long)(tm * BM + wave * (BM / 4) + srow) * lda + scol;
  const bf16* Bb = Bt + (long)(tn * BN + wave * (BN / 4) + srow) * ldb + scol;

  auto stage = [&](int buf, int k0) {
#pragma unroll
    for (int i = 0; i < BM / 64; i++)
      gload16(Ab + (long)(i * 16) * lda + k0, sA + buf * BM * 32 + (wave * (BM / 4) + i * 16) * 32);
#pragma unroll
    for (int i = 0; i < BN / 64; i++)
      gload16(Bb + (long)(i * 16) * ldb + k0, sB + buf * BN * 32 + (wave * (BN / 4) + i * 16) * 32);
  };

  stage(0, 0);
  __syncthreads();

  f32x4 acc[FM][FN] = {};
  int cur = 0;
  for (int k0 = 0; k0 < K; k0 += 32) {
    if (k0 + 32 < K) stage(cur ^ 1, k0 + 32);
    bf16x8v af[FM], bfr[FN];
#pragma unroll
    for (int m = 0; m < FM; m++)
      af[m] = *reinterpret_cast<const bf16x8v*>(
          sA + cur * BM * 32 + (wr * 16 * FM + m * 16 + l16) * 32 + lhi * 8);
#pragma unroll
    for (int n = 0; n < FN; n++)
      bfr[n] = *reinterpret_cast<const bf16x8v*>(
          sB + cur * BN * 32 + (wc * 16 * FN + n * 16 + l16) * 32 + lhi * 8);
#pragma unroll
    for (int m = 0; m < FM; m++)
#pragma unroll
      for (int n = 0; n < FN; n++)
        acc[m][n] = __builtin_amdgcn_mfma_f32_16x16x32_bf16(af[m], bfr[n], acc[m][n], 0, 0, 0);
    if (k0 + 32 < K) {
      __syncthreads();
      cur ^= 1;
    }
  }

#pragma unroll
  for (int m = 0; m < FM; m++) {
    const int gr0 = tm * BM + wr * 16 * FM + m * 16 + lhi * 4;
#pragma unroll
    for (int n = 0; n < FN; n++) {
      const int gc = tn * BN + wc * 16 * FN + n * 16 + l16;
      const float bv = bias ? bias[gc] : 0.f;
      if (VTOUT && gc >= vcol0) {
        const int vc = gc - vcol0;
        bf16* vdst = vtout + ((long)(((gr0 >> 10) << 3) + (vc >> 6)) << 16)
                           + ((long)(vc & 63) << 10) + (gr0 & 1023);
        union { short sh[4]; u32x2 u2; } pk;
#pragma unroll
        for (int j = 0; j < 4; j++) pk.sh[j] = f2bs(acc[m][n][j] + bv);
        *reinterpret_cast<u32x2*>(vdst) = pk.u2;
      } else {
#pragma unroll
        for (int j = 0; j < 4; j++) {
          float v = acc[m][n][j] + bv;
          if (RELU) v = fmaxf(v, 0.f);
          if constexpr (sizeof(TC) == 4)
            C[(long)(gr0 + j) * ldc + gc] = v;
          else
            C[(long)(gr0 + j) * ldc + gc] = f2b(v);
        }
      }
    }
  }
}

// ---------------- gemm8_k: 256^2 tile, BK=64, 8 waves, swizzled LDS, counted vmcnt
template <bool RELU, bool VTOUT>
__global__ __launch_bounds__(512, 2) void gemm8_k(
    const bf16* __restrict__ A, int lda, const bf16* __restrict__ Bt, int ldb,
    bf16* __restrict__ C, int ldc, const float* __restrict__ bias, int K, int tiles_n,
    bf16* __restrict__ vtout, int vcol0) {
  __shared__ bf16 sA[2][256 * 64];
  __shared__ bf16 sB[2][256 * 64];
  const int NKT = K >> 6;
  const int bid = blockIdx.x;
  const int tm8 = ((int)gridDim.x / tiles_n) >> 3;
  const int r8 = bid >> 3;
  const int tm = (bid & 7) + ((r8 % tm8) << 3);
  const int tn = r8 / tm8;
  const int tid = threadIdx.x, wave = tid >> 6, lane = tid & 63;
  const int wm = wave >> 2, wn = wave & 3;
  const int l16 = lane & 15, lhi = lane >> 4;

  const int srow = tid >> 3;
  const int scol = ((tid & 7) ^ (srow & 7)) * 8;
  const bf16* Ag = A + (long)(tm * 256 + srow) * lda + scol;
  const bf16* Bg = Bt + (long)(tn * 256 + srow) * ldb + scol;

  auto stage = [&](int buf, int kt) {
    const int kofs = kt * 64;
#pragma unroll
    for (int p = 0; p < 4; p++)
      gload16(Ag + (long)(p * 64) * lda + kofs, &sA[buf][(p * 64 + wave * 8) * 64]);
#pragma unroll
    for (int p = 0; p < 4; p++)
      gload16(Bg + (long)(p * 64) * ldb + kofs, &sB[buf][(p * 64 + wave * 8) * 64]);
  };

  stage(0, 0);
  if (NKT > 1) stage(1, 1);

  f32x4 acc[8][4] = {};
  const int sxor = (l16 & 7) << 4;
  const int aoff0 = ((lhi * 16) ^ sxor) >> 1;
  const int aoff1 = ((64 + lhi * 16) ^ sxor) >> 1;

#pragma unroll 1
  for (int kt = 0; kt < NKT; kt++) {
    const int buf = kt & 1;
    vmwait((kt + 1 < NKT) ? 8 : 0);
    SBAR();
    __builtin_amdgcn_s_barrier();
    SBAR();
#pragma unroll
    for (int ks = 0; ks < 2; ks++) {
      const int ao = ks ? aoff1 : aoff0;
      bf16x8v bfr[4];
#pragma unroll
      for (int n = 0; n < 4; n++)
        bfr[n] = *reinterpret_cast<const bf16x8v*>(
            &sB[buf][(wn * 64 + n * 16 + l16) * 64 + ao]);
#pragma unroll
      for (int mh = 0; mh < 2; mh++) {
        bf16x8v af[4];
#pragma unroll
        for (int mm = 0; mm < 4; mm++)
          af[mm] = *reinterpret_cast<const bf16x8v*>(
              &sA[buf][(wm * 128 + (mh * 4 + mm) * 16 + l16) * 64 + ao]);
        __builtin_amdgcn_s_setprio(1);
#pragma unroll
        for (int mm = 0; mm < 4; mm++)
#pragma unroll
          for (int n = 0; n < 4; n++)
            acc[mh * 4 + mm][n] = __builtin_amdgcn_mfma_f32_16x16x32_bf16(
                af[mm], bfr[n], acc[mh * 4 + mm][n], 0, 0, 0);
        __builtin_amdgcn_s_setprio(0);
      }
    }
    SBAR();
    __builtin_amdgcn_s_barrier();
    SBAR();
    if (kt + 2 < NKT) stage(buf, kt + 2);
  }

#pragma unroll
  for (int m = 0; m < 8; m++) {
    const int gr0 = tm * 256 + wm * 128 + m * 16 + lhi * 4;
#pragma unroll
    for (int n = 0; n < 4; n++) {
      const int gc = tn * 256 + wn * 64 + n * 16 + l16;
      const float bv = bias[gc];
      if (VTOUT && gc >= vcol0) {
        const int vc = gc - vcol0;
        bf16* vdst = vtout + ((long)(((gr0 >> 10) << 3) + (vc >> 6)) << 16)
                           + ((long)(vc & 63) << 10) + (gr0 & 1023);
        union { short sh[4]; u32x2 u2; } pk;
#pragma unroll
        for (int j = 0; j < 4; j++) pk.sh[j] = f2bs(acc[m][n][j] + bv);
        *reinterpret_cast<u32x2*>(vdst) = pk.u2;
      } else {
#pragma unroll
        for (int j = 0; j < 4; j++) {
          float v = acc[m][n][j] + bv;
          if (RELU) v = fmaxf(v, 0.f);
          C[(long)(gr0 + j) * ldc + gc] = f2b(v);
        }
      }
    }
  }
}

// ---------------- attention core: counted-vmcnt pipelined 2-pass flash ----------
// (round-8 verified schedule) attn region of smem = 34816 B:
// Kst[3][2048] | Vst[3][2048] | pst[4][1280]. qB supplied by caller.
template <bool CAUSAL>
DEVI void attn_core(char* smem, const bf16x8v qB[2][2],
                    const bf16* __restrict__ Kb, int ldk,
                    const bf16* __restrict__ Vb,
                    float* __restrict__ Pg, bf16* __restrict__ cb,
                    int nun, int nchw, int nchb) {
  bf16* Kst = (bf16*)smem;
  bf16* Vst = Kst + 3 * 2048;
  bf16* pst = Vst + 3 * 2048;
  const int tid = threadIdx.x, wave = tid >> 6, lane = tid & 63;
  const int l16 = lane & 15, lhi = lane >> 4;

  const bf16* ksrc = Kb + (long)(tid >> 3) * ldk + ((tid & 7) ^ ((tid >> 3) & 7)) * 8;
  const bf16* vsrc = Vb + (long)(tid >> 2) * 1024 + ((tid & 3) ^ ((tid >> 2) & 3)) * 8;

  int kfo[2][2];
#pragma unroll
  for (int cc = 0; cc < 2; cc++) {
    const int r = cc * 16 + l16;
#pragma unroll
    for (int ks = 0; ks < 2; ks++)
      kfo[cc][ks] = r * 64 + (((ks * 64 + lhi * 16) ^ ((r & 7) << 4)) >> 1);
  }
  int vfo[4];
#pragma unroll
  for (int n = 0; n < 4; n++) {
    const int r = n * 16 + l16;
    vfo[n] = r * 32 + (((lhi * 16) ^ ((r & 3) << 4)) >> 1);
  }

  float ll[2] = {0.f, 0.f};

  // ================ pass 1: l-sum only (no max), K triple-buffered ================
  gload16(ksrc, Kst + wave * 512);
  gload16(ksrc + (long)32 * ldk, Kst + 2048 + wave * 512);
#pragma unroll 1
  for (int ch = 0; ch < nchb; ch++) {
    if (ch + 1 < nchb) vmwait(1); else vmwait(0);
    SBAR();
    __builtin_amdgcn_s_barrier();
    SBAR();
    if (ch + 2 < nchb)
      gload16(ksrc + (long)(ch + 2) * 32 * ldk, Kst + ((ch + 2) % 3) * 2048 + wave * 512);
    if (ch < nchw) {
      const int bo = (ch % 3) * 2048;
      bf16x8v kf[2][2];
#pragma unroll
      for (int cc = 0; cc < 2; cc++)
#pragma unroll
        for (int ks = 0; ks < 2; ks++)
          kf[cc][ks] = *reinterpret_cast<const bf16x8v*>(&Kst[bo + kfo[cc][ks]]);
      const bool diag = CAUSAL && (ch == nun);
#pragma unroll
      for (int m = 0; m < 2; m++) {
        f32x4 s0 = {}, s1 = {};
        s0 = __builtin_amdgcn_mfma_f32_16x16x32_bf16(kf[0][0], qB[m][0], s0, 0, 0, 0);
        s0 = __builtin_amdgcn_mfma_f32_16x16x32_bf16(kf[0][1], qB[m][1], s0, 0, 0, 0);
        s1 = __builtin_amdgcn_mfma_f32_16x16x32_bf16(kf[1][0], qB[m][0], s1, 0, 0, 0);
        s1 = __builtin_amdgcn_mfma_f32_16x16x32_bf16(kf[1][1], qB[m][1], s1, 0, 0, 0);
        if (diag) {
          const int rq = m * 16 + l16;
#pragma unroll
          for (int j = 0; j < 4; j++) {
            s0[j] = (lhi * 4 + j <= rq) ? s0[j] : -1e30f;   // exp2 -> 0 exactly
            s1[j] = (16 + lhi * 4 + j <= rq) ? s1[j] : -1e30f;
          }
        }
        float sum = 0.f;
#pragma unroll
        for (int j = 0; j < 4; j++) sum += ex2(s0[j]) + ex2(s1[j]);
        ll[m] += sum;
      }
    }
  }
  __syncthreads();  // pass boundary

  float il[2];
#pragma unroll
  for (int m = 0; m < 2; m++) {
    float lo = ll[m];
    lo += __shfl_xor(lo, 16);
    lo += __shfl_xor(lo, 32);
    il[m] = 1.f / lo;
  }

  // ================ pass 2: P write + PV, K+V triple-buffered ================
  f32x4 pv[2][4] = {};
  gload16(ksrc, Kst + wave * 512);
  gload16(vsrc, Vst + wave * 512);
  gload16(ksrc + (long)32 * ldk, Kst + 2048 + wave * 512);
  gload16(vsrc + 32, Vst + 2048 + wave * 512);
#pragma unroll 1
  for (int ch = 0; ch < nchb; ch++) {
    const int Sa = (ch >= 2 && ch - 2 < nchw) ? 4 : 0;
    const int Lr = (ch + 1 < nchb) ? 2 : 0;
    const int Sb = (ch >= 1 && ch - 1 < nchw) ? 4 : 0;
    vmwait(Sa + Lr + Sb);
    SBAR();
    __builtin_amdgcn_s_barrier();
    SBAR();
    if (ch + 2 < nchb) {
      gload16(ksrc + (long)(ch + 2) * 32 * ldk, Kst + ((ch + 2) % 3) * 2048 + wave * 512);
      gload16(vsrc + (ch + 2) * 32, Vst + ((ch + 2) % 3) * 2048 + wave * 512);
    }
    if (ch < nchw) {
      const int kc = ch * 32;
      const int bo = (ch % 3) * 2048;
      bf16x8v kf[2][2], vf[4];
#pragma unroll
      for (int cc = 0; cc < 2; cc++)
#pragma unroll
        for (int ks = 0; ks < 2; ks++)
          kf[cc][ks] = *reinterpret_cast<const bf16x8v*>(&Kst[bo + kfo[cc][ks]]);
#pragma unroll
      for (int n = 0; n < 4; n++)
        vf[n] = *reinterpret_cast<const bf16x8v*>(&Vst[bo + vfo[n]]);
      const bool diag = CAUSAL && (ch == nun);
#pragma unroll
      for (int m = 0; m < 2; m++) {
        f32x4 s0 = {}, s1 = {};
        s0 = __builtin_amdgcn_mfma_f32_16x16x32_bf16(kf[0][0], qB[m][0], s0, 0, 0, 0);
        s0 = __builtin_amdgcn_mfma_f32_16x16x32_bf16(kf[0][1], qB[m][1], s0, 0, 0, 0);
        s1 = __builtin_amdgcn_mfma_f32_16x16x32_bf16(kf[1][0], qB[m][0], s1, 0, 0, 0);
        s1 = __builtin_amdgcn_mfma_f32_16x16x32_bf16(kf[1][1], qB[m][1], s1, 0, 0, 0);
        if (diag) {
          const int rq = m * 16 + l16;
#pragma unroll
          for (int j = 0; j < 4; j++) {
            s0[j] = (lhi * 4 + j <= rq) ? s0[j] : -1e30f;
            s1[j] = (16 + lhi * 4 + j <= rq) ? s1[j] : -1e30f;
          }
        }
        f32x4 p0, p1;
#pragma unroll
        for (int j = 0; j < 4; j++) {
          p0[j] = ex2(s0[j]) * il[m];
          p1[j] = ex2(s1[j]) * il[m];
        }
        const int prow = (m * 16 + l16) * 40;
        union { short s[4]; u32x2 u; } pk0, pk1;
#pragma unroll
        for (int j = 0; j < 4; j++) { pk0.s[j] = f2bs(p0[j]); pk1.s[j] = f2bs(p1[j]); }
        *reinterpret_cast<u32x2*>(&pst[wave * 1280 + prow + lhi * 4]) = pk0.u;
        *reinterpret_cast<u32x2*>(&pst[wave * 1280 + prow + 16 + lhi * 4]) = pk1.u;
      }
#pragma unroll
      for (int m = 0; m < 2; m++) {
        bf16x8v pa = *reinterpret_cast<const bf16x8v*>(
            &pst[wave * 1280 + (m * 16 + l16) * 40 + lhi * 8]);
#pragma unroll
        for (int n = 0; n < 4; n++)
          pv[m][n] = __builtin_amdgcn_mfma_f32_16x16x32_bf16(pa, vf[n], pv[m][n], 0, 0, 0);
      }
      // flush P from pst (bf16 -> f32 bitshift): 4 nt-stores, 8 rows x 128B each
#pragma unroll
      for (int f = 0; f < 4; f++) {
        const int row = f * 8 + (lane >> 3);
        u32x2 raw = *reinterpret_cast<const u32x2*>(
            &pst[wave * 1280 + row * 40 + (lane & 7) * 4]);
        union { unsigned int u; float fl; } c0, c1, c2, c3;
        c0.u = raw[0] << 16; c1.u = raw[0] & 0xffff0000u;
        c2.u = raw[1] << 16; c3.u = raw[1] & 0xffff0000u;
        f32x4 val = {c0.fl, c1.fl, c2.fl, c3.fl};
        __builtin_nontemporal_store(
            val, reinterpret_cast<f32x4*>(Pg + (long)row * 1024 + kc + (lane & 7) * 4));
      }
    }
  }

#pragma unroll
  for (int m = 0; m < 2; m++)
#pragma unroll
    for (int n = 0; n < 4; n++)
#pragma unroll
      for (int j = 0; j < 4; j++)
        cb[(long)(m * 16 + lhi * 4 + j) * 512 + n * 16 + l16] = f2b(pv[m][n][j]);
}

// self-attn wrapper: qB loaded from global (qkv)
DEVI void attn_self_body(int bid, char* smem,
                         const bf16* __restrict__ Qm, int ldq,
                         const bf16* __restrict__ Km, int ldk,
                         const bf16* __restrict__ vt,
                         float* __restrict__ P, bf16* __restrict__ ctx) {
  const int bh = bid & 63;
  const int g = bid >> 6;
  const int qx = (g < 4) ? g : 11 - g;  // anti-correlated pairs
  const int b = bh >> 3, h = bh & 7;
  const int wave = threadIdx.x >> 6, lane = threadIdx.x & 63;
  const int l16 = lane & 15, lhi = lane >> 4;
  const int q0 = qx * 128 + wave * 32;
  const bf16* Qb = Qm + (long)(b * 1024 + q0) * ldq + h * 64;
  bf16x8v qB[2][2];
#pragma unroll
  for (int m = 0; m < 2; m++)
#pragma unroll
    for (int ks = 0; ks < 2; ks++)
      qB[m][ks] = *reinterpret_cast<const bf16x8v*>(
          Qb + (long)(m * 16 + l16) * ldq + ks * 32 + lhi * 8);
  attn_core<true>(smem, qB,
                  Km + (long)b * 1024 * ldk + h * 64, ldk,
                  vt + (long)bh * 64 * 1024,
                  P + (long)bh * 1024 * 1024 + (long)q0 * 1024,
                  ctx + (long)(b * 1024 + q0) * 512 + h * 64,
                  q0 >> 5, (q0 >> 5) + 1, qx * 4 + 4);
}

// merged: 0..511 self-attn, 512..1023 kv2 GEMM (+fused vt2), 1024+ deferred
// weight transposes (independent; consumed only by later nodes).
__global__ __launch_bounds__(256) void attn_gemm_k(
    const bf16* __restrict__ Qm, int ldq, const bf16* __restrict__ Km, int ldk,
    const bf16* __restrict__ vt, float* __restrict__ P, bf16* __restrict__ ctx,
    const bf16* __restrict__ A, int lda, const bf16* __restrict__ Bt, int ldb,
    bf16* __restrict__ C, int ldc, const float* __restrict__ bias, int K, int tiles_n,
    bf16* __restrict__ vt2, WPack5 wp) {
  __shared__ __align__(16) char smem[34816];
  if (blockIdx.x < 512) {
    attn_self_body(blockIdx.x, smem, Qm, ldq, Km, ldk, vt, P, ctx);
  } else if (blockIdx.x < 1024) {
    bf16* sA = (bf16*)smem;
    gemm_body<4, 4, bf16, false, true>(blockIdx.x - 512, 512, A, lda, Bt, ldb,
                                       C, ldc, bias, K, tiles_n, sA, sA + 8192,
                                       vt2, 512);
  } else {
    wtrans_body((int)blockIdx.x - 1024, wp, (float*)smem);
  }
}

// ---------------- fused q2-projection + cross-attention ----------------
// Per block (bh, qx): Q tile [128 rows][64 depth] = out1b @ wq2t^T (+bias),
// dbuf-staged mini-GEMM (counted vmcnt(3)), bounced through swizzled LDS
// qtile -> qB frags -> unchanged non-causal attn core.
__global__ __launch_bounds__(256) void q2attn_k(
    const bf16* __restrict__ out1b, const bf16* __restrict__ wq2t,
    const float* __restrict__ bq2s,
    const bf16* __restrict__ Km, const bf16* __restrict__ vt,
    float* __restrict__ P, bf16* __restrict__ ctx) {
  __shared__ __align__(16) char smem[51200];  // attn 34816 + qtile 16384
  const int bh = blockIdx.x & 63, qx = blockIdx.x >> 6;
  const int b = bh >> 3, h = bh & 7;
  const int tid = threadIdx.x, wave = tid >> 6, lane = tid & 63;
  const int l16 = lane & 15, lhi = lane >> 4;

  // ---- Phase A: Q = out1b @ wq2t^T, 128x64, K=512 (16 k-steps, dbuf) ----
  bf16* sQA = (bf16*)smem;         // 2 x 4096 elems (128 rows x 32)
  bf16* sQB = sQA + 8192;          // 2 x 2048 elems (64 rows x 32)
  const bf16* Asrc0 = out1b + (long)(b * 1024 + qx * 128 + (tid >> 2)) * 512
                      + ((tid & 3) ^ ((tid >> 2) & 3)) * 8;
  const bf16* Asrc1 = Asrc0 + (long)64 * 512;
  const bf16* Bsrc = wq2t + (long)(h * 64 + (tid >> 2)) * 512
                     + ((tid & 3) ^ ((tid >> 2) & 3)) * 8;

  auto qstage = [&](int buf, int kt) {
    const int k0 = kt * 32;
    gload16(Asrc0 + k0, sQA + buf * 4096 + tid * 8);
    gload16(Asrc1 + k0, sQA + buf * 4096 + 2048 + tid * 8);
    gload16(Bsrc + k0, sQB + buf * 2048 + tid * 8);
  };

  qstage(0, 0);
  qstage(1, 1);

  f32x4 qacc[2][4] = {};
#pragma unroll 1
  for (int kt = 0; kt < 16; kt++) {
    const int buf = kt & 1;
    vmwait((kt + 1 < 16) ? 3 : 0);
    SBAR();
    __builtin_amdgcn_s_barrier();
    SBAR();
    bf16x8v af[2], bfr[4];
#pragma unroll
    for (int m = 0; m < 2; m++) {
      const int r = wave * 32 + m * 16 + l16;
      af[m] = *reinterpret_cast<const bf16x8v*>(
          &sQA[buf * 4096 + r * 32 + ((lhi ^ (r & 3)) * 8)]);
    }
#pragma unroll
    for (int n = 0; n < 4; n++) {
      const int r = n * 16 + l16;
      bfr[n] = *reinterpret_cast<const bf16x8v*>(
          &sQB[buf * 2048 + r * 32 + ((lhi ^ (r & 3)) * 8)]);
    }
    __builtin_amdgcn_s_setprio(1);
#pragma unroll
    for (int m = 0; m < 2; m++)
#pragma unroll
      for (int n = 0; n < 4; n++)
        qacc[m][n] = __builtin_amdgcn_mfma_f32_16x16x32_bf16(af[m], bfr[n], qacc[m][n], 0, 0, 0);
    __builtin_amdgcn_s_setprio(0);
    SBAR();
    __builtin_amdgcn_s_barrier();
    SBAR();
    if (kt + 2 < 16) qstage(buf, kt + 2);
  }

  // ---- bounce Q through swizzled qtile (row stride 128 B, XOR (r&7)<<4) ----
  char* qt = smem + 34816;
#pragma unroll
  for (int m = 0; m < 2; m++)
#pragma unroll
    for (int n = 0; n < 4; n++)
#pragma unroll
      for (int j = 0; j < 4; j++) {
        const int r = wave * 32 + m * 16 + lhi * 4 + j;
        const int d = n * 16 + l16;
        *reinterpret_cast<bf16*>(qt + r * 128 + ((d * 2) ^ ((r & 7) << 4))) =
            f2b(qacc[m][n][j] + bq2s[h * 64 + d]);
      }
  __syncthreads();
  bf16x8v qB[2][2];
#pragma unroll
  for (int m = 0; m < 2; m++) {
    const int rq = wave * 32 + m * 16 + l16;
#pragma unroll
    for (int ks = 0; ks < 2; ks++)
      qB[m][ks] = *reinterpret_cast<const bf16x8v*>(
          qt + rq * 128 + ((ks * 64 + lhi * 16) ^ ((rq & 7) << 4)));
  }
  __syncthreads();  // all qtile reads + GEMM LDS reads done -> core may reuse region

  // ---- Phase B: non-causal attn core ----
  const int q0 = qx * 128 + wave * 32;
  attn_core<false>(smem, qB,
                   Km + (long)b * 1024 * 1024 + h * 64, 1024,
                   vt + (long)bh * 64 * 1024,
                   P + (long)bh * 1024 * 1024 + (long)q0 * 1024,
                   ctx + (long)(b * 1024 + q0) * 512 + h * 64,
                   32, 32, 32);
}

// ---------------- GEMM + residual add + LayerNorm fused epilogue ----------------
template <typename TR>
__global__ __launch_bounds__(512) void gemm_ln_k(
    const bf16* __restrict__ A, int lda, const bf16* __restrict__ Bt,
    const float* __restrict__ bias, const TR* __restrict__ resid,
    const float* __restrict__ gamma, const float* __restrict__ beta,
    float* __restrict__ outf, bf16* __restrict__ outb, int K) {
  __shared__ bf16 sA[2][32 * 32];
  __shared__ bf16 sB[2][512 * 32];
  __shared__ float red[2][32][8];
  __shared__ f32x2 mr[32];
  const int tm = blockIdx.x;
  const int tid = threadIdx.x, wave = tid >> 6, lane = tid & 63;
  const int l16 = lane & 15, lhi = lane >> 4;

  const int srow = tid >> 2;
  const int sgran = ((tid & 3) ^ (srow & 3)) * 8;
  const bf16* Asrc = A + (long)(tm * 32 + srow) * lda + sgran;
  const bf16* Bsrc = Bt + (long)srow * K + sgran;

  auto stage = [&](int buf, int kt) {
    const int k0 = kt * 32;
    if (tid < 128) gload16(Asrc + k0, &sA[buf][(tid >> 6) * 512]);
#pragma unroll
    for (int p = 0; p < 4; p++)
      gload16(Bsrc + (long)(p * 128) * K + k0, &sB[buf][p * 4096 + wave * 512]);
  };

  const int NK = K >> 5;
  stage(0, 0);
  if (NK > 1) stage(1, 1);
  const int W = (wave < 2) ? 5 : 4;

  f32x4 acc[2][4] = {};
#pragma unroll 1
  for (int kt = 0; kt < NK; kt++) {
    const int buf = kt & 1;
    vmwait((kt + 1 < NK) ? W : 0);
    SBAR();
    __builtin_amdgcn_s_barrier();
    SBAR();
    bf16x8v af[2], bfr[4];
#pragma unroll
    for (int m = 0; m < 2; m++) {
      const int r = m * 16 + l16;
      af[m] = *reinterpret_cast<const bf16x8v*>(&sA[buf][r * 32 + ((lhi ^ (r & 3)) * 8)]);
    }
#pragma unroll
    for (int n = 0; n < 4; n++) {
      const int r = wave * 64 + n * 16 + l16;
      bfr[n] = *reinterpret_cast<const bf16x8v*>(&sB[buf][r * 32 + ((lhi ^ (r & 3)) * 8)]);
    }
    __builtin_amdgcn_s_setprio(1);
#pragma unroll
    for (int m = 0; m < 2; m++)
#pragma unroll
      for (int n = 0; n < 4; n++)
        acc[m][n] = __builtin_amdgcn_mfma_f32_16x16x32_bf16(af[m], bfr[n], acc[m][n], 0, 0, 0);
    __builtin_amdgcn_s_setprio(0);
    SBAR();
    __builtin_amdgcn_s_barrier();
    SBAR();
    if (kt + 2 < NK) stage(buf, kt + 2);
  }

  float bv[4], gm[4], bt[4];
#pragma unroll
  for (int n = 0; n < 4; n++) {
    const int gc = wave * 64 + n * 16 + l16;
    bv[n] = bias[gc]; gm[n] = gamma[gc]; bt[n] = beta[gc];
  }
  float v[2][4][4], rs[2][4], rq[2][4];
#pragma unroll
  for (int m = 0; m < 2; m++)
#pragma unroll
    for (int j = 0; j < 4; j++) { rs[m][j] = 0.f; rq[m][j] = 0.f; }
#pragma unroll
  for (int m = 0; m < 2; m++) {
#pragma unroll
    for (int j = 0; j < 4; j++) {
      const long grow = tm * 32 + m * 16 + lhi * 4 + j;
#pragma unroll
      for (int n = 0; n < 4; n++) {
        const int gc = wave * 64 + n * 16 + l16;
        const float val = acc[m][n][j] + bv[n] + ldf(resid + grow * 512 + gc);
        v[m][n][j] = val;
        rs[m][j] += val;
        rq[m][j] += val * val;
      }
    }
  }
#pragma unroll
  for (int m = 0; m < 2; m++)
#pragma unroll
    for (int j = 0; j < 4; j++)
#pragma unroll
      for (int off = 1; off <= 8; off <<= 1) {
        rs[m][j] += __shfl_xor(rs[m][j], off);
        rq[m][j] += __shfl_xor(rq[m][j], off);
      }
  if (l16 == 0) {
#pragma unroll
    for (int m = 0; m < 2; m++)
#pragma unroll
      for (int j = 0; j < 4; j++) {
        red[0][m * 16 + lhi * 4 + j][wave] = rs[m][j];
        red[1][m * 16 + lhi * 4 + j][wave] = rq[m][j];
      }
  }
  __syncthreads();
  if (tid < 32) {
    float s = 0.f, q = 0.f;
#pragma unroll
    for (int w = 0; w < 8; w++) { s += red[0][tid][w]; q += red[1][tid][w]; }
    const float mean = s * (1.f / 512.f);
    const float var = q * (1.f / 512.f) - mean * mean;
    f32x2 o = {mean, rsqrtf(var + 1e-5f)};
    mr[tid] = o;
  }
  __syncthreads();
#pragma unroll
  for (int m = 0; m < 2; m++) {
#pragma unroll
    for (int j = 0; j < 4; j++) {
      const int row = m * 16 + lhi * 4 + j;
      const f32x2 mrv = mr[row];
      const long grow = tm * 32 + row;
#pragma unroll
      for (int n = 0; n < 4; n++) {
        const int gc = wave * 64 + n * 16 + l16;
        const float o = (v[m][n][j] - mrv[0]) * mrv[1] * gm[n] + bt[n];
        if (outf) outf[grow * 512 + gc] = o;
        if (outb) outb[grow * 512 + gc] = f2b(o);
      }
    }
  }
}

extern "C" void kernel_launch(void* const* d_in, const int* in_sizes, int n_in,
                              void* d_out, int out_size, void* d_ws, size_t ws_size,
                              hipStream_t stream) {
  const float* x = (const float*)d_in[0];
  const float* enc = (const float*)d_in[1];
  const float* wq1 = (const float*)d_in[4];  const float* bq1 = (const float*)d_in[5];
  const float* wk1 = (const float*)d_in[6];  const float* bk1 = (const float*)d_in[7];
  const float* wv1 = (const float*)d_in[8];  const float* bv1 = (const float*)d_in[9];
  const float* wo1 = (const float*)d_in[10]; const float* bo1 = (const float*)d_in[11];
  const float* wq2 = (const float*)d_in[12]; const float* bq2 = (const float*)d_in[13];
  const float* wk2 = (const float*)d_in[14]; const float* bk2 = (const float*)d_in[15];
  const float* wv2 = (const float*)d_in[16]; const float* bv2 = (const float*)d_in[17];
  const float* wo2 = (const float*)d_in[18]; const float* bo2 = (const float*)d_in[19];
  const float* wff1 = (const float*)d_in[20]; const float* bff1 = (const float*)d_in[21];
  const float* wff2 = (const float*)d_in[22]; const float* bff2 = (const float*)d_in[23];
  const float* gamma1 = (const float*)d_in[24]; const float* beta1 = (const float*)d_in[25];
  const float* gamma2 = (const float*)d_in[26]; const float* beta2 = (const float*)d_in[27];
  const float* gamma3 = (const float*)d_in[28]; const float* beta3 = (const float*)d_in[29];

  float* out3 = (float*)d_out;
  float* sa_w = out3 + (long)8 * 1024 * 512;
  float* ca_w = sa_w + (long)64 * 1024 * 1024;

  char* w = (char*)d_ws;
  auto alloc = [&](long bytes) { char* p = w; w += (bytes + 255) & ~255L; return p; };
  bf16* xb     = (bf16*)alloc(8192L * 512 * 2);
  bf16* encb   = (bf16*)alloc(8192L * 512 * 2);
  bf16* wqkv1t = (bf16*)alloc(1536L * 512 * 2);
  bf16* wo1t   = (bf16*)alloc(512L * 512 * 2);
  bf16* wq2t   = (bf16*)alloc(512L * 512 * 2);
  bf16* wkv2t  = (bf16*)alloc(1024L * 512 * 2);
  bf16* wo2t   = (bf16*)alloc(512L * 512 * 2);
  bf16* wff1t  = (bf16*)alloc(2048L * 512 * 2);
  bf16* wff2t  = (bf16*)alloc(512L * 2048 * 2);
  float* bcat  = (float*)alloc(3072L * 4);  // bq1*S | bk1 | bv1 | bk2 | bv2 | bq2*S
  bf16* qkv    = (bf16*)alloc(8192L * 1536 * 2);
  bf16* kv2    = (bf16*)alloc(8192L * 1024 * 2);
  bf16* vt     = (bf16*)alloc(64L * 64 * 1024 * 2);
  bf16* vt2    = (bf16*)alloc(64L * 64 * 1024 * 2);
  bf16* ctx    = (bf16*)alloc(8192L * 512 * 2);
  bf16* out1b  = (bf16*)alloc(8192L * 512 * 2);
  bf16* out2b  = (bf16*)alloc(8192L * 512 * 2);
  bf16* ffh    = qkv;  // alias: qkv dead by FFN; spans 32MB

  // ---- prep (casts + early weights + bias) ----
  PrepPack pp;
  pp.x = x; pp.enc = enc; pp.xb = xb; pp.encb = encb;
  pp.w.d[0] = {wq1, wqkv1t,               512, 512, 0,    QSCL};
  pp.w.d[1] = {wk1, wqkv1t + 512L * 512,  512, 512, 256,  1.f};
  pp.w.d[2] = {wv1, wqkv1t + 1024L * 512, 512, 512, 512,  1.f};
  pp.w.d[3] = {wk2, wkv2t,                512, 512, 768,  1.f};
  pp.w.d[4] = {wv2, wkv2t + 512L * 512,   512, 512, 1024, 1.f};
  pp.bsrc[0] = bq1; pp.bsrc[1] = bk1; pp.bsrc[2] = bv1;
  pp.bsrc[3] = bk2; pp.bsrc[4] = bv2; pp.bsrc[5] = bq2;
  pp.bscl[0] = QSCL; pp.bscl[1] = 1.f; pp.bscl[2] = 1.f;
  pp.bscl[3] = 1.f;  pp.bscl[4] = 1.f; pp.bscl[5] = QSCL;
  pp.bdst = bcat;
  prep_k<<<9478, 256, 0, stream>>>(pp);

  // deferred weight transposes (overlap with self-attention)
  WPack5 wd;
  wd.d[0] = {wo1,  wo1t,  512,  512,  0,    1.f};
  wd.d[1] = {wq2,  wq2t,  512,  512,  256,  QSCL};
  wd.d[2] = {wo2,  wo2t,  512,  512,  512,  1.f};
  wd.d[3] = {wff1, wff1t, 512,  2048, 768,  1.f};
  wd.d[4] = {wff2, wff2t, 2048, 512,  1792, 1.f};

  // ================= self attention (+ overlapped kv2 + weight prep) ========
  gemm8_k<false, true><<<192, 512, 0, stream>>>(
      xb, 512, wqkv1t, 512, qkv, 1536, bcat, 512, 6, vt, 1024);  // V -> vt fused
  attn_gemm_k<<<3840, 256, 0, stream>>>(
      qkv, 1536, qkv + 512, 1536, vt, sa_w, ctx,
      encb, 512, wkv2t, 512, kv2, 1024, bcat + 1536, 512, 8, vt2, wd);
  gemm_ln_k<float><<<256, 512, 0, stream>>>(
      ctx, 512, wo1t, bo1, x, gamma1, beta1, nullptr, out1b, 512);

  // ================= cross attention (q2 projection fused) =================
  q2attn_k<<<512, 256, 0, stream>>>(
      out1b, wq2t, bcat + 2560, kv2, vt2, ca_w, ctx);
  gemm_ln_k<bf16><<<256, 512, 0, stream>>>(
      ctx, 512, wo2t, bo2, out1b, gamma2, beta2, nullptr, out2b, 512);

  // ================= FFN =================
  gemm8_k<true, false><<<256, 512, 0, stream>>>(
      out2b, 512, wff1t, 512, ffh, 2048, bff1, 512, 8, nullptr, 0);
  gemm_ln_k<bf16><<<256, 512, 0, stream>>>(
      ffh, 2048, wff2t, bff2, out2b, gamma3, beta3, out3, nullptr, 2048);
}